// Round 12
// baseline (234.754 us; speedup 1.0000x reference)
//
#include <hip/hip_runtime.h>

typedef __attribute__((ext_vector_type(8))) short short8_t;
typedef __attribute__((ext_vector_type(4))) float f32x4_t;

#define N_NODES  4096
#define E0_EDGES 262144
#define E_TOTAL  266240
#define SPLITS   12
#define BUCKET_CAP 160                     // Poisson(65) degree; P(deg>=160) ~ 1e-21

// ---------- helpers ----------
__device__ __forceinline__ float bf2f(unsigned short u){
  union { unsigned int i; float f; } v; v.i = ((unsigned int)u) << 16; return v.f;
}
__device__ __forceinline__ unsigned short f2bf(float f){
  union { float f; unsigned int i; } v; v.f = f;
  unsigned int r = (v.i + 0x7FFFu + ((v.i >> 16) & 1u)) >> 16;
  return (unsigned short)r;
}
__device__ __forceinline__ unsigned int cvtpk_bf16(float lo, float hi){
  unsigned int r;
  asm volatile("v_cvt_pk_bf16_f32 %0, %1, %2" : "=v"(r) : "v"(lo), "v"(hi));
  return r;
}
template<int CTRL>
__device__ __forceinline__ float dpp_add(float x){
  int v = __builtin_amdgcn_update_dpp(0, __float_as_int(x), CTRL, 0xF, 0xF, true);
  return x + __int_as_float(v);
}
__device__ __forceinline__ float rowsum16(float x){
  x = dpp_add<0xB1>(x); x = dpp_add<0x4E>(x); x = dpp_add<0x124>(x); x = dpp_add<0x128>(x);
  return x;
}
// raw barrier: drains LDS ops only; prefetched global loads stay in flight
__device__ __forceinline__ void wg_barrier(){
  asm volatile("s_waitcnt lgkmcnt(0)" ::: "memory");
  __builtin_amdgcn_s_barrier();
  asm volatile("" ::: "memory");
}
__device__ __forceinline__ uint4 cvt8_f32_to_bf16(float4 f0, float4 f1){
  union { unsigned short u[8]; uint4 q; } o;
  o.u[0]=f2bf(f0.x); o.u[1]=f2bf(f0.y); o.u[2]=f2bf(f0.z); o.u[3]=f2bf(f0.w);
  o.u[4]=f2bf(f1.x); o.u[5]=f2bf(f1.y); o.u[6]=f2bf(f1.z); o.u[7]=f2bf(f1.w);
  return o.q;
}

// ---------- prep: x convert + weight transpose-convert + zero cnt ----------
struct TJob { const float* src; unsigned short* dst; int rows, cols, tile0; };
struct TJobs { TJob j[10]; };

__global__ __launch_bounds__(256) void prep_kernel(const float* __restrict__ x, unsigned short* __restrict__ xb,
                                                   TJobs jobs, int tb, int* __restrict__ zp){
  __shared__ unsigned short tile[64 * 64];
  int b = blockIdx.x, t = threadIdx.x;
  if (b < 3072){
    int i = (b * 256 + t) * 4;
    float4 v = *(const float4*)&x[i];
    union { unsigned short u[4]; uint2 q; } o;
    o.u[0] = f2bf(v.x); o.u[1] = f2bf(v.y); o.u[2] = f2bf(v.z); o.u[3] = f2bf(v.w);
    *(uint2*)&xb[i] = o.q;
    return;
  }
  if (b < 3072 + tb){
    int bb = b - 3072;
    int ji = 0;
    #pragma unroll
    for (int k = 1; k < 10; k++) if (bb >= jobs.j[k].tile0) ji = k;
    TJob J = jobs.j[ji];
    int lt = bb - J.tile0;
    int tpr = J.cols >> 6;
    int tr = lt / tpr, tc = lt - tr * tpr;
    #pragma unroll
    for (int i2 = 0; i2 < 2; i2++){
      int e = i2 * 2048 + t * 8;
      int nl = e >> 6, c8 = e & 63;
      const float* sp = &J.src[(size_t)(tr * 64 + nl) * J.cols + tc * 64 + c8];
      float4 v0 = *(const float4*)sp;
      float4 v1 = *(const float4*)(sp + 4);
      *(uint4*)&tile[nl * 64 + (((c8 >> 3) ^ ((nl >> 3) & 7)) * 8)] = cvt8_f32_to_bf16(v0, v1);
    }
    __syncthreads();
    #pragma unroll
    for (int i2 = 0; i2 < 2; i2++){
      int e = i2 * 2048 + t * 8;
      int cl = e >> 6, n8 = e & 63;
      union { unsigned short u[8]; uint4 q; } o;
      #pragma unroll
      for (int j = 0; j < 8; j++){
        int row = n8 + j;
        o.u[j] = tile[row * 64 + (((cl >> 3) ^ ((row >> 3) & 7)) * 8) + (cl & 7)];
      }
      *(uint4*)&J.dst[(size_t)(tc * 64 + cl) * J.rows + tr * 64 + n8] = o.q;
    }
    return;
  }
  int i = (b - 3072 - tb) * 256 + t;
  if (i < N_NODES) zp[i] = 0;
}

// ---------- bucket scatter: no CSR, fixed-capacity per-node buckets ----------
__global__ __launch_bounds__(256) void scatter_kernel(const int* __restrict__ ei, int* __restrict__ cnt,
                                                      int* __restrict__ csrc){
  int e = blockIdx.x * 256 + threadIdx.x;
  if (e >= E_TOTAL) return;
  int s, d;
  if (e < E0_EDGES){ s = ei[e]; d = ei[E0_EDGES + e]; }
  else { s = d = e - E0_EDGES; }
  int pos = atomicAdd(&cnt[d], 1);
  csrc[d * BUCKET_CAP + pos] = s;
}

// ---------- generic bf16 MFMA GEMM (double-buffered) ----------
struct GJob { const unsigned short* Wt; const float* bias; float* outF; unsigned short* outB; unsigned short* outT; float scale; };
struct GJobs { GJob j[3]; };

__global__ __launch_bounds__(256) void gemm_kernel(const unsigned short* __restrict__ A, GJobs jobs,
                                                   int K, int Nc, int relu){
  __shared__ unsigned short lds[8192];   // 2 bufs x (A 2048 + B 2048)
  const int t = threadIdx.x;
  const GJob job = jobs.j[blockIdx.z];
  const int lane = t & 63, w = t >> 6;
  const int wm = w >> 1, wn = w & 1;
  const int c16 = lane & 15, g = lane >> 4;
  const int bm = blockIdx.x, bn = blockIdx.y;

  const int srow = t >> 2, schunk = t & 3;
  const unsigned short* Ag = A      + (size_t)(bm * 64 + srow) * K + schunk * 8;
  const unsigned short* Bg = job.Wt + (size_t)(bn * 64 + srow) * K + schunk * 8;
  const int swz = srow * 32 + ((schunk ^ ((srow >> 1) & 3)) * 8);

  const int arow0 = wm * 32 + c16, arow1 = arow0 + 16;
  const int aoff0 = arow0 * 32 + ((g ^ ((arow0 >> 1) & 3)) * 8);
  const int aoff1 = arow1 * 32 + ((g ^ ((arow1 >> 1) & 3)) * 8);
  const int bcol0 = wn * 32 + c16, bcol1 = bcol0 + 16;
  const int boff0 = 2048 + bcol0 * 32 + ((g ^ ((bcol0 >> 1) & 3)) * 8);
  const int boff1 = 2048 + bcol1 * 32 + ((g ^ ((bcol1 >> 1) & 3)) * 8);

  f32x4_t acc[2][2] = {};
  const int nk = K >> 5;

  {
    uint4 av = *(const uint4*)(Ag);
    uint4 bv = *(const uint4*)(Bg);
    *(uint4*)&lds[swz]        = av;
    *(uint4*)&lds[2048 + swz] = bv;
  }
  int cur = 0;
  for (int i = 0; i < nk; i++){
    const bool pf = (i + 1) < nk;
    uint4 av, bv;
    if (pf){
      av = *(const uint4*)(Ag + (i + 1) * 32);
      bv = *(const uint4*)(Bg + (i + 1) * 32);
    }
    wg_barrier();
    const int base = cur * 4096;
    union { uint4 u; short8_t s; } a0, a1, b0, b1;
    a0.u = *(const uint4*)&lds[base + aoff0];
    a1.u = *(const uint4*)&lds[base + aoff1];
    b0.u = *(const uint4*)&lds[base + boff0];
    b1.u = *(const uint4*)&lds[base + boff1];
    acc[0][0] = __builtin_amdgcn_mfma_f32_16x16x32_bf16(a0.s, b0.s, acc[0][0], 0, 0, 0);
    acc[0][1] = __builtin_amdgcn_mfma_f32_16x16x32_bf16(a0.s, b1.s, acc[0][1], 0, 0, 0);
    acc[1][0] = __builtin_amdgcn_mfma_f32_16x16x32_bf16(a1.s, b0.s, acc[1][0], 0, 0, 0);
    acc[1][1] = __builtin_amdgcn_mfma_f32_16x16x32_bf16(a1.s, b1.s, acc[1][1], 0, 0, 0);
    if (pf){
      const int nb = (cur ^ 1) * 4096;
      *(uint4*)&lds[nb + swz]        = av;
      *(uint4*)&lds[nb + 2048 + swz] = bv;
      cur ^= 1;
    }
  }

  #pragma unroll
  for (int fm = 0; fm < 2; fm++){
    #pragma unroll
    for (int fn = 0; fn < 2; fn++){
      int col = bn * 64 + wn * 32 + fn * 16 + c16;
      float bia = job.bias ? job.bias[col] : 0.f;
      float vv[4];
      #pragma unroll
      for (int r = 0; r < 4; r++){
        float v = (acc[fm][fn][r] + bia) * job.scale;
        if (relu) v = fmaxf(v, 0.f);
        vv[r] = v;
      }
      int row0 = bm * 64 + wm * 32 + fm * 16 + g * 4;
      if (job.outF){
        #pragma unroll
        for (int r = 0; r < 4; r++) job.outF[(size_t)(row0 + r) * Nc + col] = vv[r];
      }
      if (job.outB){
        #pragma unroll
        for (int r = 0; r < 4; r++) job.outB[(size_t)(row0 + r) * Nc + col] = f2bf(vv[r]);
      }
      if (job.outT){
        union { unsigned short u[4]; uint2 q; } pk;
        #pragma unroll
        for (int r = 0; r < 4; r++) pk.u[r] = f2bf(vv[r]);
        *(uint2*)&job.outT[(size_t)col * 4096 + row0] = pk.q;
      }
    }
  }
}

// ---------- GATv2 gather: wave = one edge slot, 2x unrolled; bucket layout ----------
__global__ __launch_bounds__(256) void gat_gather(const unsigned short* __restrict__ xs, const unsigned short* __restrict__ xd,
                                                  const float* __restrict__ att, const float* __restrict__ bias,
                                                  const int* __restrict__ cnt, const int* __restrict__ csrc,
                                                  unsigned short* __restrict__ outB, float* __restrict__ outF){
  __shared__ float combL[4][256];
  __shared__ float combS[4][4];
  const int i = blockIdx.x, t = threadIdx.x;
  const int lane = t & 63, w = t >> 6;
  float xdc[4], attc[4];
  {
    uint2 xv = *(const uint2*)&xd[i * 256 + lane * 4];
    xdc[0] = bf2f((unsigned short)(xv.x & 0xffff)); xdc[1] = bf2f((unsigned short)(xv.x >> 16));
    xdc[2] = bf2f((unsigned short)(xv.y & 0xffff)); xdc[3] = bf2f((unsigned short)(xv.y >> 16));
    float4 av = *(const float4*)&att[lane * 4];
    attc[0] = av.x; attc[1] = av.y; attc[2] = av.z; attc[3] = av.w;
  }
  const int b1 = cnt[i];
  const int* bucket = csrc + i * BUCKET_CAP;
  float acc0 = 0.f, acc1 = 0.f, acc2 = 0.f, acc3 = 0.f, ssum = 0.f;
  int p = w;
  for (; p + 4 < b1; p += 8){
    int sA = bucket[p], sB = bucket[p + 4];
    uint2 xa = *(const uint2*)&xs[sA * 256 + lane * 4];
    uint2 xb = *(const uint2*)&xs[sB * 256 + lane * 4];
    float a0 = bf2f((unsigned short)(xa.x & 0xffff)), a1 = bf2f((unsigned short)(xa.x >> 16));
    float a2 = bf2f((unsigned short)(xa.y & 0xffff)), a3 = bf2f((unsigned short)(xa.y >> 16));
    float b0_ = bf2f((unsigned short)(xb.x & 0xffff)), b1_ = bf2f((unsigned short)(xb.x >> 16));
    float b2_ = bf2f((unsigned short)(xb.y & 0xffff)), b3_ = bf2f((unsigned short)(xb.y >> 16));
    float va0 = a0 + xdc[0]; va0 = (va0 > 0.f) ? va0 : 0.2f * va0;
    float va1 = a1 + xdc[1]; va1 = (va1 > 0.f) ? va1 : 0.2f * va1;
    float va2 = a2 + xdc[2]; va2 = (va2 > 0.f) ? va2 : 0.2f * va2;
    float va3 = a3 + xdc[3]; va3 = (va3 > 0.f) ? va3 : 0.2f * va3;
    float vb0 = b0_ + xdc[0]; vb0 = (vb0 > 0.f) ? vb0 : 0.2f * vb0;
    float vb1 = b1_ + xdc[1]; vb1 = (vb1 > 0.f) ? vb1 : 0.2f * vb1;
    float vb2 = b2_ + xdc[2]; vb2 = (vb2 > 0.f) ? vb2 : 0.2f * vb2;
    float vb3 = b3_ + xdc[3]; vb3 = (vb3 > 0.f) ? vb3 : 0.2f * vb3;
    float eA = rowsum16(va0 * attc[0] + va1 * attc[1] + va2 * attc[2] + va3 * attc[3]);
    float eB = rowsum16(vb0 * attc[0] + vb1 * attc[1] + vb2 * attc[2] + vb3 * attc[3]);
    float pA = __expf(eA), pB = __expf(eB);
    ssum += pA + pB;
    acc0 += pA * a0 + pB * b0_; acc1 += pA * a1 + pB * b1_;
    acc2 += pA * a2 + pB * b2_; acc3 += pA * a3 + pB * b3_;
  }
  if (p < b1){
    int s = bucket[p];
    uint2 xv = *(const uint2*)&xs[s * 256 + lane * 4];
    float x0 = bf2f((unsigned short)(xv.x & 0xffff)), x1 = bf2f((unsigned short)(xv.x >> 16));
    float x2 = bf2f((unsigned short)(xv.y & 0xffff)), x3 = bf2f((unsigned short)(xv.y >> 16));
    float v0 = x0 + xdc[0]; v0 = (v0 > 0.f) ? v0 : 0.2f * v0;
    float v1 = x1 + xdc[1]; v1 = (v1 > 0.f) ? v1 : 0.2f * v1;
    float v2 = x2 + xdc[2]; v2 = (v2 > 0.f) ? v2 : 0.2f * v2;
    float v3 = x3 + xdc[3]; v3 = (v3 > 0.f) ? v3 : 0.2f * v3;
    float e = rowsum16(v0 * attc[0] + v1 * attc[1] + v2 * attc[2] + v3 * attc[3]);
    float pe = __expf(e);
    ssum += pe;
    acc0 += pe * x0; acc1 += pe * x1; acc2 += pe * x2; acc3 += pe * x3;
  }
  combL[w][lane * 4 + 0] = acc0; combL[w][lane * 4 + 1] = acc1;
  combL[w][lane * 4 + 2] = acc2; combL[w][lane * 4 + 3] = acc3;
  if ((lane & 15) == 0) combS[w][lane >> 4] = ssum;
  __syncthreads();
  float atot = combL[0][t] + combL[1][t] + combL[2][t] + combL[3][t];
  int hh = t >> 6;
  float stot = combS[0][hh] + combS[1][hh] + combS[2][hh] + combS[3][hh];
  float o = atot / (stot + 1e-16f) + bias[t];
  o = fmaxf(o, 0.f);
  outB[i * 256 + t] = f2bf(o);
  if (outF) outF[i * 256 + t] = o;
}

// ---------- flash attention: 512 thr, 256q/block, SINGLE-buffered K/V (48KB LDS -> 3 blocks/CU) ----------
// SPLITS=12 (uneven: splits 0-3 get 6 KV-tiles, 4-11 get 5) -> grid 768 = 3 blocks/CU resident.
// Register prefetch spans the compute phase; two barriers/tile guard the single LDS buffer.
// Q is prescaled by 0.125*log2(e) in the QKV GEMM epilogue -> P = exp2(S') = exp(S/8).
__global__ __launch_bounds__(512, 6) void attn_kernel(const unsigned short* __restrict__ qb, const unsigned short* __restrict__ kb,
                                                      const unsigned short* __restrict__ vt,
                                                      _Float16* __restrict__ Opart, float* __restrict__ Ol){
  __shared__ unsigned short K_lds[4096];      // [kv][dk], chunk ^ ((kv>>1)&7)
  __shared__ unsigned short V_lds[4096];      // [d][kv],  chunk ^ (d&7)
  __shared__ unsigned short P_lds[8][2048];   // per wave [32 q][64 kv], chunk ^ (q&7)
  const int t = threadIdx.x, lane = t & 63, w = t >> 6;
  const int c16 = lane & 15, g = lane >> 4;
  const int h = blockIdx.y, bq = blockIdx.x, sp = blockIdx.z;

  const int ntiles = (sp < 4) ? 6 : 5;
  const int tile0  = (sp < 4) ? sp * 6 : 24 + (sp - 4) * 5;
  const int kv_lo  = tile0 * 64;

  const int sr = t >> 3, sc = (t & 7) * 8;
  const int kw = sr * 64 + (((t & 7) ^ ((sr >> 1) & 7)) * 8);
  const int vw = sr * 64 + (((t & 7) ^ (sr & 7)) * 8);

  short8_t qa[2][2];
  #pragma unroll
  for (int qm = 0; qm < 2; qm++){
    int qrow = bq * 256 + w * 32 + qm * 16 + c16;
    union { uint4 u; short8_t s; } cv0, cv1;
    cv0.u = *(const uint4*)&qb[(size_t)qrow * 256 + h * 64 + g * 8];
    cv1.u = *(const uint4*)&qb[(size_t)qrow * 256 + h * 64 + 32 + g * 8];
    qa[qm][0] = cv0.s; qa[qm][1] = cv1.s;
  }

  f32x4_t oacc[2][4] = {};       // O^T[d = fn*16+g*4+r][q = qm*16+c16]
  float lsum[2] = {0.f, 0.f};

  {
    uint4 k0 = *(const uint4*)&kb[(size_t)(kv_lo + sr) * 256 + h * 64 + sc];
    uint4 v0 = *(const uint4*)&vt[(size_t)(h * 64 + sr) * 4096 + kv_lo + sc];
    *(uint4*)&K_lds[kw] = k0;
    *(uint4*)&V_lds[vw] = v0;
  }

  for (int ti = 0; ti < ntiles; ti++){
    const bool pf = (ti + 1) < ntiles;
    uint4 nk, nv;
    if (pf){
      int kvn = kv_lo + (ti + 1) * 64;
      nk = *(const uint4*)&kb[(size_t)(kvn + sr) * 256 + h * 64 + sc];
      nv = *(const uint4*)&vt[(size_t)(h * 64 + sr) * 4096 + kvn + sc];
    }
    wg_barrier();      // tile ti's LDS writes visible; vmcnt prefetch stays in flight
    unsigned short* Pw = P_lds[w];

    // S^T = K Q^T : lane holds S[q = qm*16+c16][kv = fn*16+g*4+r]
    f32x4_t sacc[2][4] = {};
    #pragma unroll
    for (int kd = 0; kd < 2; kd++){
      #pragma unroll
      for (int fn = 0; fn < 4; fn++){
        union { uint4 u; short8_t s; } kf;
        kf.u = *(const uint4*)&K_lds[(fn * 16 + c16) * 64 + (((kd * 4 + g) ^ ((c16 >> 1) & 7)) * 8)];
        sacc[0][fn] = __builtin_amdgcn_mfma_f32_16x16x32_bf16(kf.s, qa[0][kd], sacc[0][fn], 0, 0, 0);
        sacc[1][fn] = __builtin_amdgcn_mfma_f32_16x16x32_bf16(kf.s, qa[1][kd], sacc[1][fn], 0, 0, 0);
      }
    }

    // softmax without max-subtraction; P = 2^S' (Q carries 0.125*log2e)
    #pragma unroll
    for (int qm = 0; qm < 2; qm++){
      float ps = 0.f;
      int row = qm * 16 + c16;
      #pragma unroll
      for (int fn = 0; fn < 4; fn++){
        float p0 = __builtin_exp2f(sacc[qm][fn][0]);
        float p1 = __builtin_exp2f(sacc[qm][fn][1]);
        float p2 = __builtin_exp2f(sacc[qm][fn][2]);
        float p3 = __builtin_exp2f(sacc[qm][fn][3]);
        ps += (p0 + p1) + (p2 + p3);
        uint2 pk;
        pk.x = cvtpk_bf16(p0, p1);
        pk.y = cvtpk_bf16(p2, p3);
        int chunk = (fn * 2 + (g >> 1)) ^ (c16 & 7);
        *(uint2*)&Pw[row * 64 + chunk * 8 + (g & 1) * 4] = pk;
      }
      ps += __shfl_xor(ps, 16, 64);
      ps += __shfl_xor(ps, 32, 64);
      lsum[qm] += ps;
    }

    // O^T += V^T P^T (K=32 MFMA, b128 LDS reads)
    #pragma unroll
    for (int kd2 = 0; kd2 < 2; kd2++){
      const int ch = (((kd2 * 4 + g) ^ (c16 & 7)) * 8);
      union { uint4 u; short8_t s; } pt0, pt1;
      pt0.u = *(const uint4*)&Pw[c16 * 64 + ch];
      pt1.u = *(const uint4*)&Pw[(16 + c16) * 64 + ch];
      #pragma unroll
      for (int fn = 0; fn < 4; fn++){
        union { uint4 u; short8_t s; } vf;
        vf.u = *(const uint4*)&V_lds[(fn * 16 + c16) * 64 + ch];
        oacc[0][fn] = __builtin_amdgcn_mfma_f32_16x16x32_bf16(vf.s, pt0.s, oacc[0][fn], 0, 0, 0);
        oacc[1][fn] = __builtin_amdgcn_mfma_f32_16x16x32_bf16(vf.s, pt1.s, oacc[1][fn], 0, 0, 0);
      }
    }

    if (pf){
      wg_barrier();    // all reads of tile ti done before overwrite
      *(uint4*)&K_lds[kw] = nk;
      *(uint4*)&V_lds[vw] = nv;
    }
  }

  // f16 partials (bf16 fails: cancellation-amplified, R5; f16 mantissa is 8x finer)
  const int sh = sp * 4 + h;
  #pragma unroll
  for (int qm = 0; qm < 2; qm++){
    int node = bq * 256 + w * 32 + qm * 16 + c16;
    #pragma unroll
    for (int fn = 0; fn < 4; fn++){
      union { _Float16 h[4]; uint2 q; } pk;
      #pragma unroll
      for (int r = 0; r < 4; r++) pk.h[r] = (_Float16)oacc[qm][fn][r];
      *(uint2*)&Opart[((size_t)sh * N_NODES + node) * 64 + fn * 16 + g * 4] = pk.q;
    }
    if (g == 0) Ol[(size_t)sh * N_NODES + node] = lsum[qm];
  }
}

// ---------- Wo GEMM + split-K combine (f16 partials) + residual + LN + classifier, fused ----------
__global__ __launch_bounds__(256) void wo_ln_cls_kernel(const _Float16* __restrict__ Opart, const float* __restrict__ Ol,
                                                        const unsigned short* __restrict__ Wt, const float* __restrict__ bo,
                                                        const float* __restrict__ h2f, const float* __restrict__ gg,
                                                        const float* __restrict__ bb,
                                                        const unsigned short* __restrict__ Wt1, const float* __restrict__ b1,
                                                        const float* __restrict__ w2, const float* __restrict__ b2,
                                                        float* __restrict__ out){
  __shared__ unsigned short Ab[2][512];
  __shared__ unsigned short Bb[2][8192];
  __shared__ unsigned short Cb[2][4096];
  __shared__ unsigned short hl[16 * 264];    // LN output tile, pad 8
  __shared__ float red1[4][16], red2[4][16];
  __shared__ float cred0[4][16], cred1[4][16];
  __shared__ float Ls[64];     // 1/L for [node16][head4]
  const int t = threadIdx.x, lane = t & 63, w = t >> 6;
  const int c16 = lane & 15, g = lane >> 4;
  const int bm = blockIdx.x;

  const int arow = t >> 2, achk = t & 3;
  const int aswz = arow * 32 + ((achk ^ ((arow >> 1) & 3)) * 8);
  const int bq_ = t >> 2, bchk = t & 3;

  if (t < 64){
    int node = bm * 16 + (t >> 2), h = t & 3;
    float L = 0.f;
    #pragma unroll
    for (int s = 0; s < SPLITS; s++) L += Ol[(size_t)(s * 4 + h) * N_NODES + node];
    Ls[t] = 1.f / L;
  }
  __syncthreads();

  const int afr = c16 * 32 + ((g ^ ((c16 >> 1) & 3)) * 8);
  int bfr[4];
  #pragma unroll
  for (int fn = 0; fn < 4; fn++){
    int col = w * 64 + fn * 16 + c16;
    bfr[fn] = col * 32 + ((g ^ ((col >> 1) & 3)) * 8);
  }

  const int anode = bm * 16 + arow;
  auto combineA = [&](int k0) -> uint4 {
    int c0 = k0 + achk * 8;
    int hh = c0 >> 6, d0 = c0 & 63;
    float a[8] = {0.f,0.f,0.f,0.f,0.f,0.f,0.f,0.f};
    #pragma unroll
    for (int s = 0; s < SPLITS; s++){
      union { uint4 q; _Float16 h[8]; } u;
      u.q = *(const uint4*)&Opart[((size_t)(s * 4 + hh) * N_NODES + anode) * 64 + d0];
      #pragma unroll
      for (int j = 0; j < 8; j++) a[j] += (float)u.h[j];
    }
    float Li = Ls[(arow << 2) | hh];
    union { unsigned short u[8]; uint4 q; } o;
    #pragma unroll
    for (int j = 0; j < 8; j++) o.u[j] = f2bf(a[j] * Li);
    return o.q;
  };

  f32x4_t acc[4] = {};
  {
    if (t < 64) *(uint4*)&Ab[0][aswz] = combineA(0);
    #pragma unroll
    for (int j = 0; j < 4; j++){
      int col = j * 64 + bq_;
      *(uint4*)&Bb[0][col * 32 + ((bchk ^ ((col >> 1) & 3)) * 8)] = *(const uint4*)&Wt[(size_t)col * 256 + bchk * 8];
    }
  }
  int cur = 0;
  for (int i = 0; i < 8; i++){
    const bool pf = i < 7;
    uint4 pb[4];
    uint4 av;
    int k1 = (i + 1) * 32;
    if (pf){
      if (t < 64) av = combineA(k1);
      #pragma unroll
      for (int j = 0; j < 4; j++){
        int col = j * 64 + bq_;
        pb[j] = *(const uint4*)&Wt[(size_t)col * 256 + k1 + bchk * 8];
      }
    }
    wg_barrier();
    union { uint4 u; short8_t s; } a, b;
    a.u = *(const uint4*)&Ab[cur][afr];
    #pragma unroll
    for (int fn = 0; fn < 4; fn++){
      b.u = *(const uint4*)&Bb[cur][bfr[fn]];
      acc[fn] = __builtin_amdgcn_mfma_f32_16x16x32_bf16(a.s, b.s, acc[fn], 0, 0, 0);
    }
    if (pf){
      if (t < 64) *(uint4*)&Ab[cur ^ 1][aswz] = av;
      #pragma unroll
      for (int j = 0; j < 4; j++){
        int col = j * 64 + bq_;
        *(uint4*)&Bb[cur ^ 1][col * 32 + ((bchk ^ ((col >> 1) & 3)) * 8)] = pb[j];
      }
      cur ^= 1;
    }
  }

  // epilogue: bias + residual, register-space LN, result -> LDS tile hl
  float vv[4][4];
  #pragma unroll
  for (int fn = 0; fn < 4; fn++){
    int col = w * 64 + fn * 16 + c16;
    float bia = bo[col];
    #pragma unroll
    for (int r = 0; r < 4; r++)
      vv[fn][r] = acc[fn][r] + bia + h2f[(size_t)(bm * 16 + g * 4 + r) * 256 + col];
  }
  #pragma unroll
  for (int r = 0; r < 4; r++){
    float a = 0.f, b = 0.f;
    #pragma unroll
    for (int fn = 0; fn < 4; fn++){ a += vv[fn][r]; b += vv[fn][r] * vv[fn][r]; }
    a = rowsum16(a); b = rowsum16(b);
    if (c16 == 0){ red1[w][g * 4 + r] = a; red2[w][g * 4 + r] = b; }
  }
  __syncthreads();
  #pragma unroll
  for (int r = 0; r < 4; r++){
    int row = g * 4 + r;
    float S1 = red1[0][row] + red1[1][row] + red1[2][row] + red1[3][row];
    float S2 = red2[0][row] + red2[1][row] + red2[2][row] + red2[3][row];
    float mean = S1 * (1.f / 256.f);
    float var = S2 * (1.f / 256.f) - mean * mean;
    float rs = rsqrtf(var + 1e-5f);
    #pragma unroll
    for (int fn = 0; fn < 4; fn++){
      int col = w * 64 + fn * 16 + c16;
      hl[row * 264 + col] = f2bf((vv[fn][r] - mean) * rs * gg[col] + bb[col]);
    }
  }

  // ---- classifier phase: c1 = relu(hl @ W1 + b1); out = c1 @ w2 + b2 ----
  wg_barrier();
  int cfr[2];
  #pragma unroll
  for (int fn = 0; fn < 2; fn++){
    int col = w * 32 + fn * 16 + c16;
    cfr[fn] = col * 32 + ((g ^ ((col >> 1) & 3)) * 8);
  }
  f32x4_t cacc[2] = {};
  {
    #pragma unroll
    for (int j = 0; j < 2; j++){
      int col = j * 64 + bq_;
      *(uint4*)&Cb[0][col * 32 + ((bchk ^ ((col >> 1) & 3)) * 8)] = *(const uint4*)&Wt1[(size_t)col * 256 + bchk * 8];
    }
  }
  cur = 0;
  for (int i = 0; i < 8; i++){
    const bool pf = i < 7;
    uint4 pb[2];
    if (pf){
      int k1 = (i + 1) * 32;
      #pragma unroll
      for (int j = 0; j < 2; j++){
        int col = j * 64 + bq_;
        pb[j] = *(const uint4*)&Wt1[(size_t)col * 256 + k1 + bchk * 8];
      }
    }
    wg_barrier();
    union { uint4 u; short8_t s; } a, b;
    a.u = *(const uint4*)&hl[c16 * 264 + i * 32 + g * 8];
    #pragma unroll
    for (int fn = 0; fn < 2; fn++){
      b.u = *(const uint4*)&Cb[cur][cfr[fn]];
      cacc[fn] = __builtin_amdgcn_mfma_f32_16x16x32_bf16(a.s, b.s, cacc[fn], 0, 0, 0);
    }
    if (pf){
      #pragma unroll
      for (int j = 0; j < 2; j++){
        int col = j * 64 + bq_;
        *(uint4*)&Cb[cur ^ 1][col * 32 + ((bchk ^ ((col >> 1) & 3)) * 8)] = pb[j];
      }
      cur ^= 1;
    }
  }
  float cv[2][4];
  #pragma unroll
  for (int fn = 0; fn < 2; fn++){
    int col = w * 32 + fn * 16 + c16;
    float bia = b1[col];
    #pragma unroll
    for (int r = 0; r < 4; r++) cv[fn][r] = fmaxf(cacc[fn][r] + bia, 0.f);
  }
  float w20 = w2[(w * 32 + c16) * 2],      w21 = w2[(w * 32 + c16) * 2 + 1];
  float w30 = w2[(w * 32 + 16 + c16) * 2], w31 = w2[(w * 32 + 16 + c16) * 2 + 1];
  #pragma unroll
  for (int r = 0; r < 4; r++){
    float a0 = cv[0][r] * w20 + cv[1][r] * w30;
    float a1 = cv[0][r] * w21 + cv[1][r] * w31;
    a0 = rowsum16(a0); a1 = rowsum16(a1);
    if (c16 == 0){ cred0[w][g * 4 + r] = a0; cred1[w][g * 4 + r] = a1; }
  }
  __syncthreads();
  if (t < 16){
    float q0 = cred0[0][t] + cred0[1][t] + cred0[2][t] + cred0[3][t] + b2[0];
    float q1 = cred1[0][t] + cred1[1][t] + cred1[2][t] + cred1[3][t] + b2[1];
    out[(size_t)(bm * 16 + t) * 2]     = q0;
    out[(size_t)(bm * 16 + t) * 2 + 1] = q1;
  }
}

// ---------- host ----------
extern "C" void kernel_launch(void* const* d_in, const int* in_sizes, int n_in,
                              void* d_out, int out_size, void* d_ws, size_t ws_size,
                              hipStream_t stream){
  const float* x      = (const float*)d_in[0];
  const int*   ei     = (const int*)d_in[1];
  const float* emb_w  = (const float*)d_in[2];
  const float* emb_b  = (const float*)d_in[3];
  const float* g1_wl  = (const float*)d_in[4];
  const float* g1_wr  = (const float*)d_in[5];
  const float* g1_att = (const float*)d_in[6];
  const float* g1_b   = (const float*)d_in[7];
  const float* g2_wl  = (const float*)d_in[8];
  const float* g2_wr  = (const float*)d_in[9];
  const float* g2_att = (const float*)d_in[10];
  const float* g2_b   = (const float*)d_in[11];
  const float* wq     = (const float*)d_in[12];
  const float* wk     = (const float*)d_in[13];
  const float* wv     = (const float*)d_in[14];
  const float* bq     = (const float*)d_in[15];
  const float* bk     = (const float*)d_in[16];
  const float* bv     = (const float*)d_in[17];
  const float* wo     = (const float*)d_in[18];
  const float* bo     = (const float*)d_in[19];
  const float* ln_g   = (const float*)d_in[20];
  const float* ln_b   = (const float*)d_in[21];
  const float* cls_w1 = (const float*)d_in[22];
  const float* cls_b1 = (const float*)d_in[23];
  const float* cls_w2 = (const float*)d_in[24];
  const float* cls_b2 = (const float*)d_in[25];
  float* out = (float*)d_out;

  char* wsb = (char*)d_ws;
  size_t o = 0;
  auto take = [&](size_t bytes) -> char* {
    char* r = wsb + o; o += (bytes + 255) & ~(size_t)255; return r;
  };
  unsigned short* wt_emb  = (unsigned short*)take(768 * 256 * 2);
  unsigned short* wt_wl1  = (unsigned short*)take(256 * 256 * 2);
  unsigned short* wt_wr1  = (unsigned short*)take(256 * 256 * 2);
  unsigned short* wt_wl2  = (unsigned short*)take(256 * 256 * 2);
  unsigned short* wt_wr2  = (unsigned short*)take(256 * 256 * 2);
  unsigned short* wt_wq   = (unsigned short*)take(256 * 256 * 2);
  unsigned short* wt_wk   = (unsigned short*)take(256 * 256 * 2);
  unsigned short* wt_wv   = (unsigned short*)take(256 * 256 * 2);
  unsigned short* wt_wo   = (unsigned short*)take(256 * 256 * 2);
  unsigned short* wt_cls1 = (unsigned short*)take(256 * 128 * 2);
  unsigned short* x_bf    = (unsigned short*)take((size_t)4096 * 768 * 2);
  unsigned short* h0_bf   = (unsigned short*)take((size_t)4096 * 256 * 2);
  unsigned short* xs1_bf  = (unsigned short*)take((size_t)4096 * 256 * 2);
  unsigned short* xd1_bf  = (unsigned short*)take((size_t)4096 * 256 * 2);
  unsigned short* h1_bf   = (unsigned short*)take((size_t)4096 * 256 * 2);
  unsigned short* xs2_bf  = (unsigned short*)take((size_t)4096 * 256 * 2);
  unsigned short* xd2_bf  = (unsigned short*)take((size_t)4096 * 256 * 2);
  unsigned short* h2_bf   = (unsigned short*)take((size_t)4096 * 256 * 2);
  float*          h2_f    = (float*)take((size_t)4096 * 256 * 4);
  unsigned short* q_bf    = (unsigned short*)take((size_t)4096 * 256 * 2);
  unsigned short* k_bf    = (unsigned short*)take((size_t)4096 * 256 * 2);
  unsigned short* vt_bf   = (unsigned short*)take((size_t)4096 * 256 * 2);
  int* cnt  = (int*)take(4096 * 4);
  int* csrc = (int*)take((size_t)N_NODES * BUCKET_CAP * 4);
  _Float16* Opart = (_Float16*)take((size_t)SPLITS * 4 * N_NODES * 64 * 2);
  float*    Ol    = (float*)take((size_t)SPLITS * 4 * N_NODES * 4);

  // prep: x convert + weight transposes + zero cnt
  TJobs TJ;
  TJob tj[10] = {
    { emb_w,  wt_emb,  768, 256, 0 },
    { g1_wl,  wt_wl1,  256, 256, 0 },
    { g1_wr,  wt_wr1,  256, 256, 0 },
    { g2_wl,  wt_wl2,  256, 256, 0 },
    { g2_wr,  wt_wr2,  256, 256, 0 },
    { wq,     wt_wq,   256, 256, 0 },
    { wk,     wt_wk,   256, 256, 0 },
    { wv,     wt_wv,   256, 256, 0 },
    { wo,     wt_wo,   256, 256, 0 },
    { cls_w1, wt_cls1, 256, 128, 0 },
  };
  int tb = 0;
  for (int i = 0; i < 10; i++){
    tj[i].tile0 = tb;
    tb += (tj[i].rows >> 6) * (tj[i].cols >> 6);
    TJ.j[i] = tj[i];
  }
  prep_kernel<<<3072 + tb + 16, 256, 0, stream>>>(x, x_bf, TJ, tb, cnt);

  // bucket scatter (no CSR)
  scatter_kernel<<<(E_TOTAL + 255) / 256, 256, 0, stream>>>(ei, cnt, csrc);

  GJobs J;
  // embedding GEMM
  J = {}; J.j[0] = { wt_emb, emb_b, nullptr, h0_bf, nullptr, 1.f };
  gemm_kernel<<<dim3(64, 4, 1), 256, 0, stream>>>(x_bf, J, 768, 256, 0);
  // GAT1
  J = {}; J.j[0] = { wt_wl1, nullptr, nullptr, xs1_bf, nullptr, 1.f }; J.j[1] = { wt_wr1, nullptr, nullptr, xd1_bf, nullptr, 1.f };
  gemm_kernel<<<dim3(64, 4, 2), 256, 0, stream>>>(h0_bf, J, 256, 256, 0);
  gat_gather<<<4096, 256, 0, stream>>>(xs1_bf, xd1_bf, g1_att, g1_b, cnt, csrc, h1_bf, nullptr);
  // GAT2
  J = {}; J.j[0] = { wt_wl2, nullptr, nullptr, xs2_bf, nullptr, 1.f }; J.j[1] = { wt_wr2, nullptr, nullptr, xd2_bf, nullptr, 1.f };
  gemm_kernel<<<dim3(64, 4, 2), 256, 0, stream>>>(h1_bf, J, 256, 256, 0);
  gat_gather<<<4096, 256, 0, stream>>>(xs2_bf, xd2_bf, g2_att, g2_b, cnt, csrc, h2_bf, h2_f);
  // QKV (Q prescaled by 0.125*log2e for exp2-softmax; V written transposed via outT)
  J = {};
  J.j[0] = { wt_wq, bq, nullptr, q_bf, nullptr, 0.125f * 1.44269504f };
  J.j[1] = { wt_wk, bk, nullptr, k_bf, nullptr, 1.f };
  J.j[2] = { wt_wv, bv, nullptr, nullptr, vt_bf, 1.f };
  gemm_kernel<<<dim3(64, 4, 3), 256, 0, stream>>>(h2_bf, J, 256, 256, 0);
  // attention (f16 partials, SPLITS=12, 48KB LDS -> 3 blocks/CU)
  attn_kernel<<<dim3(16, 4, SPLITS), 512, 0, stream>>>(q_bf, k_bf, vt_bf, Opart, Ol);
  // Wo + combine + residual + LN + classifier
  wo_ln_cls_kernel<<<256, 256, 0, stream>>>(Opart, Ol, wt_wo, bo, h2_f, ln_g, ln_b,
                                            wt_cls1, cls_b1, cls_w2, cls_b2, out);

  (void)in_sizes; (void)n_in; (void)out_size; (void)ws_size;
}

// Round 13
// 150.265 us; speedup vs baseline: 1.5623x; 1.5623x over previous
//
#include <hip/hip_runtime.h>

typedef __attribute__((ext_vector_type(8))) short short8_t;
typedef __attribute__((ext_vector_type(4))) float f32x4_t;

#define N_NODES  4096
#define E0_EDGES 262144
#define E_TOTAL  266240
#define SPLITS   12
#define BUCKET_CAP 160                     // Poisson(65) degree; P(deg>=160) ~ 1e-21

// ---------- helpers ----------
__device__ __forceinline__ float bf2f(unsigned short u){
  union { unsigned int i; float f; } v; v.i = ((unsigned int)u) << 16; return v.f;
}
__device__ __forceinline__ unsigned short f2bf(float f){
  union { float f; unsigned int i; } v; v.f = f;
  unsigned int r = (v.i + 0x7FFFu + ((v.i >> 16) & 1u)) >> 16;
  return (unsigned short)r;
}
__device__ __forceinline__ unsigned int cvtpk_bf16(float lo, float hi){
  unsigned int r;
  asm volatile("v_cvt_pk_bf16_f32 %0, %1, %2" : "=v"(r) : "v"(lo), "v"(hi));
  return r;
}
template<int CTRL>
__device__ __forceinline__ float dpp_add(float x){
  int v = __builtin_amdgcn_update_dpp(0, __float_as_int(x), CTRL, 0xF, 0xF, true);
  return x + __int_as_float(v);
}
__device__ __forceinline__ float rowsum16(float x){
  x = dpp_add<0xB1>(x); x = dpp_add<0x4E>(x); x = dpp_add<0x124>(x); x = dpp_add<0x128>(x);
  return x;
}
// raw barrier: drains LDS ops only; prefetched global loads stay in flight
__device__ __forceinline__ void wg_barrier(){
  asm volatile("s_waitcnt lgkmcnt(0)" ::: "memory");
  __builtin_amdgcn_s_barrier();
  asm volatile("" ::: "memory");
}
__device__ __forceinline__ uint4 cvt8_f32_to_bf16(float4 f0, float4 f1){
  union { unsigned short u[8]; uint4 q; } o;
  o.u[0]=f2bf(f0.x); o.u[1]=f2bf(f0.y); o.u[2]=f2bf(f0.z); o.u[3]=f2bf(f0.w);
  o.u[4]=f2bf(f1.x); o.u[5]=f2bf(f1.y); o.u[6]=f2bf(f1.z); o.u[7]=f2bf(f1.w);
  return o.q;
}

// ---------- prep: x convert + weight transpose-convert + zero cnt ----------
struct TJob { const float* src; unsigned short* dst; int rows, cols, tile0; };
struct TJobs { TJob j[10]; };

__global__ __launch_bounds__(256) void prep_kernel(const float* __restrict__ x, unsigned short* __restrict__ xb,
                                                   TJobs jobs, int tb, int* __restrict__ zp){
  __shared__ unsigned short tile[64 * 64];
  int b = blockIdx.x, t = threadIdx.x;
  if (b < 3072){
    int i = (b * 256 + t) * 4;
    float4 v = *(const float4*)&x[i];
    union { unsigned short u[4]; uint2 q; } o;
    o.u[0] = f2bf(v.x); o.u[1] = f2bf(v.y); o.u[2] = f2bf(v.z); o.u[3] = f2bf(v.w);
    *(uint2*)&xb[i] = o.q;
    return;
  }
  if (b < 3072 + tb){
    int bb = b - 3072;
    int ji = 0;
    #pragma unroll
    for (int k = 1; k < 10; k++) if (bb >= jobs.j[k].tile0) ji = k;
    TJob J = jobs.j[ji];
    int lt = bb - J.tile0;
    int tpr = J.cols >> 6;
    int tr = lt / tpr, tc = lt - tr * tpr;
    #pragma unroll
    for (int i2 = 0; i2 < 2; i2++){
      int e = i2 * 2048 + t * 8;
      int nl = e >> 6, c8 = e & 63;
      const float* sp = &J.src[(size_t)(tr * 64 + nl) * J.cols + tc * 64 + c8];
      float4 v0 = *(const float4*)sp;
      float4 v1 = *(const float4*)(sp + 4);
      *(uint4*)&tile[nl * 64 + (((c8 >> 3) ^ ((nl >> 3) & 7)) * 8)] = cvt8_f32_to_bf16(v0, v1);
    }
    __syncthreads();
    #pragma unroll
    for (int i2 = 0; i2 < 2; i2++){
      int e = i2 * 2048 + t * 8;
      int cl = e >> 6, n8 = e & 63;
      union { unsigned short u[8]; uint4 q; } o;
      #pragma unroll
      for (int j = 0; j < 8; j++){
        int row = n8 + j;
        o.u[j] = tile[row * 64 + (((cl >> 3) ^ ((row >> 3) & 7)) * 8) + (cl & 7)];
      }
      *(uint4*)&J.dst[(size_t)(tc * 64 + cl) * J.rows + tr * 64 + n8] = o.q;
    }
    return;
  }
  int i = (b - 3072 - tb) * 256 + t;
  if (i < N_NODES) zp[i] = 0;
}

// ---------- bucket scatter: no CSR, fixed-capacity per-node buckets ----------
__global__ __launch_bounds__(256) void scatter_kernel(const int* __restrict__ ei, int* __restrict__ cnt,
                                                      int* __restrict__ csrc){
  int e = blockIdx.x * 256 + threadIdx.x;
  if (e >= E_TOTAL) return;
  int s, d;
  if (e < E0_EDGES){ s = ei[e]; d = ei[E0_EDGES + e]; }
  else { s = d = e - E0_EDGES; }
  int pos = atomicAdd(&cnt[d], 1);
  csrc[d * BUCKET_CAP + pos] = s;
}

// ---------- generic bf16 MFMA GEMM (double-buffered) ----------
struct GJob { const unsigned short* Wt; const float* bias; float* outF; unsigned short* outB; unsigned short* outT; float scale; };
struct GJobs { GJob j[3]; };

__global__ __launch_bounds__(256) void gemm_kernel(const unsigned short* __restrict__ A, GJobs jobs,
                                                   int K, int Nc, int relu){
  __shared__ unsigned short lds[8192];   // 2 bufs x (A 2048 + B 2048)
  const int t = threadIdx.x;
  const GJob job = jobs.j[blockIdx.z];
  const int lane = t & 63, w = t >> 6;
  const int wm = w >> 1, wn = w & 1;
  const int c16 = lane & 15, g = lane >> 4;
  const int bm = blockIdx.x, bn = blockIdx.y;

  const int srow = t >> 2, schunk = t & 3;
  const unsigned short* Ag = A      + (size_t)(bm * 64 + srow) * K + schunk * 8;
  const unsigned short* Bg = job.Wt + (size_t)(bn * 64 + srow) * K + schunk * 8;
  const int swz = srow * 32 + ((schunk ^ ((srow >> 1) & 3)) * 8);

  const int arow0 = wm * 32 + c16, arow1 = arow0 + 16;
  const int aoff0 = arow0 * 32 + ((g ^ ((arow0 >> 1) & 3)) * 8);
  const int aoff1 = arow1 * 32 + ((g ^ ((arow1 >> 1) & 3)) * 8);
  const int bcol0 = wn * 32 + c16, bcol1 = bcol0 + 16;
  const int boff0 = 2048 + bcol0 * 32 + ((g ^ ((bcol0 >> 1) & 3)) * 8);
  const int boff1 = 2048 + bcol1 * 32 + ((g ^ ((bcol1 >> 1) & 3)) * 8);

  f32x4_t acc[2][2] = {};
  const int nk = K >> 5;

  {
    uint4 av = *(const uint4*)(Ag);
    uint4 bv = *(const uint4*)(Bg);
    *(uint4*)&lds[swz]        = av;
    *(uint4*)&lds[2048 + swz] = bv;
  }
  int cur = 0;
  for (int i = 0; i < nk; i++){
    const bool pf = (i + 1) < nk;
    uint4 av, bv;
    if (pf){
      av = *(const uint4*)(Ag + (i + 1) * 32);
      bv = *(const uint4*)(Bg + (i + 1) * 32);
    }
    wg_barrier();
    const int base = cur * 4096;
    union { uint4 u; short8_t s; } a0, a1, b0, b1;
    a0.u = *(const uint4*)&lds[base + aoff0];
    a1.u = *(const uint4*)&lds[base + aoff1];
    b0.u = *(const uint4*)&lds[base + boff0];
    b1.u = *(const uint4*)&lds[base + boff1];
    acc[0][0] = __builtin_amdgcn_mfma_f32_16x16x32_bf16(a0.s, b0.s, acc[0][0], 0, 0, 0);
    acc[0][1] = __builtin_amdgcn_mfma_f32_16x16x32_bf16(a0.s, b1.s, acc[0][1], 0, 0, 0);
    acc[1][0] = __builtin_amdgcn_mfma_f32_16x16x32_bf16(a1.s, b0.s, acc[1][0], 0, 0, 0);
    acc[1][1] = __builtin_amdgcn_mfma_f32_16x16x32_bf16(a1.s, b1.s, acc[1][1], 0, 0, 0);
    if (pf){
      const int nb = (cur ^ 1) * 4096;
      *(uint4*)&lds[nb + swz]        = av;
      *(uint4*)&lds[nb + 2048 + swz] = bv;
      cur ^= 1;
    }
  }

  #pragma unroll
  for (int fm = 0; fm < 2; fm++){
    #pragma unroll
    for (int fn = 0; fn < 2; fn++){
      int col = bn * 64 + wn * 32 + fn * 16 + c16;
      float bia = job.bias ? job.bias[col] : 0.f;
      float vv[4];
      #pragma unroll
      for (int r = 0; r < 4; r++){
        float v = (acc[fm][fn][r] + bia) * job.scale;
        if (relu) v = fmaxf(v, 0.f);
        vv[r] = v;
      }
      int row0 = bm * 64 + wm * 32 + fm * 16 + g * 4;
      if (job.outF){
        #pragma unroll
        for (int r = 0; r < 4; r++) job.outF[(size_t)(row0 + r) * Nc + col] = vv[r];
      }
      if (job.outB){
        #pragma unroll
        for (int r = 0; r < 4; r++) job.outB[(size_t)(row0 + r) * Nc + col] = f2bf(vv[r]);
      }
      if (job.outT){
        union { unsigned short u[4]; uint2 q; } pk;
        #pragma unroll
        for (int r = 0; r < 4; r++) pk.u[r] = f2bf(vv[r]);
        *(uint2*)&job.outT[(size_t)col * 4096 + row0] = pk.q;
      }
    }
  }
}

// ---------- GATv2 gather: wave = one edge slot, 2x unrolled; bucket layout ----------
__global__ __launch_bounds__(256) void gat_gather(const unsigned short* __restrict__ xs, const unsigned short* __restrict__ xd,
                                                  const float* __restrict__ att, const float* __restrict__ bias,
                                                  const int* __restrict__ cnt, const int* __restrict__ csrc,
                                                  unsigned short* __restrict__ outB, float* __restrict__ outF){
  __shared__ float combL[4][256];
  __shared__ float combS[4][4];
  const int i = blockIdx.x, t = threadIdx.x;
  const int lane = t & 63, w = t >> 6;
  float xdc[4], attc[4];
  {
    uint2 xv = *(const uint2*)&xd[i * 256 + lane * 4];
    xdc[0] = bf2f((unsigned short)(xv.x & 0xffff)); xdc[1] = bf2f((unsigned short)(xv.x >> 16));
    xdc[2] = bf2f((unsigned short)(xv.y & 0xffff)); xdc[3] = bf2f((unsigned short)(xv.y >> 16));
    float4 av = *(const float4*)&att[lane * 4];
    attc[0] = av.x; attc[1] = av.y; attc[2] = av.z; attc[3] = av.w;
  }
  const int b1 = cnt[i];
  const int* bucket = csrc + i * BUCKET_CAP;
  float acc0 = 0.f, acc1 = 0.f, acc2 = 0.f, acc3 = 0.f, ssum = 0.f;
  int p = w;
  for (; p + 4 < b1; p += 8){
    int sA = bucket[p], sB = bucket[p + 4];
    uint2 xa = *(const uint2*)&xs[sA * 256 + lane * 4];
    uint2 xb = *(const uint2*)&xs[sB * 256 + lane * 4];
    float a0 = bf2f((unsigned short)(xa.x & 0xffff)), a1 = bf2f((unsigned short)(xa.x >> 16));
    float a2 = bf2f((unsigned short)(xa.y & 0xffff)), a3 = bf2f((unsigned short)(xa.y >> 16));
    float b0_ = bf2f((unsigned short)(xb.x & 0xffff)), b1_ = bf2f((unsigned short)(xb.x >> 16));
    float b2_ = bf2f((unsigned short)(xb.y & 0xffff)), b3_ = bf2f((unsigned short)(xb.y >> 16));
    float va0 = a0 + xdc[0]; va0 = (va0 > 0.f) ? va0 : 0.2f * va0;
    float va1 = a1 + xdc[1]; va1 = (va1 > 0.f) ? va1 : 0.2f * va1;
    float va2 = a2 + xdc[2]; va2 = (va2 > 0.f) ? va2 : 0.2f * va2;
    float va3 = a3 + xdc[3]; va3 = (va3 > 0.f) ? va3 : 0.2f * va3;
    float vb0 = b0_ + xdc[0]; vb0 = (vb0 > 0.f) ? vb0 : 0.2f * vb0;
    float vb1 = b1_ + xdc[1]; vb1 = (vb1 > 0.f) ? vb1 : 0.2f * vb1;
    float vb2 = b2_ + xdc[2]; vb2 = (vb2 > 0.f) ? vb2 : 0.2f * vb2;
    float vb3 = b3_ + xdc[3]; vb3 = (vb3 > 0.f) ? vb3 : 0.2f * vb3;
    float eA = rowsum16(va0 * attc[0] + va1 * attc[1] + va2 * attc[2] + va3 * attc[3]);
    float eB = rowsum16(vb0 * attc[0] + vb1 * attc[1] + vb2 * attc[2] + vb3 * attc[3]);
    float pA = __expf(eA), pB = __expf(eB);
    ssum += pA + pB;
    acc0 += pA * a0 + pB * b0_; acc1 += pA * a1 + pB * b1_;
    acc2 += pA * a2 + pB * b2_; acc3 += pA * a3 + pB * b3_;
  }
  if (p < b1){
    int s = bucket[p];
    uint2 xv = *(const uint2*)&xs[s * 256 + lane * 4];
    float x0 = bf2f((unsigned short)(xv.x & 0xffff)), x1 = bf2f((unsigned short)(xv.x >> 16));
    float x2 = bf2f((unsigned short)(xv.y & 0xffff)), x3 = bf2f((unsigned short)(xv.y >> 16));
    float v0 = x0 + xdc[0]; v0 = (v0 > 0.f) ? v0 : 0.2f * v0;
    float v1 = x1 + xdc[1]; v1 = (v1 > 0.f) ? v1 : 0.2f * v1;
    float v2 = x2 + xdc[2]; v2 = (v2 > 0.f) ? v2 : 0.2f * v2;
    float v3 = x3 + xdc[3]; v3 = (v3 > 0.f) ? v3 : 0.2f * v3;
    float e = rowsum16(v0 * attc[0] + v1 * attc[1] + v2 * attc[2] + v3 * attc[3]);
    float pe = __expf(e);
    ssum += pe;
    acc0 += pe * x0; acc1 += pe * x1; acc2 += pe * x2; acc3 += pe * x3;
  }
  combL[w][lane * 4 + 0] = acc0; combL[w][lane * 4 + 1] = acc1;
  combL[w][lane * 4 + 2] = acc2; combL[w][lane * 4 + 3] = acc3;
  if ((lane & 15) == 0) combS[w][lane >> 4] = ssum;
  __syncthreads();
  float atot = combL[0][t] + combL[1][t] + combL[2][t] + combL[3][t];
  int hh = t >> 6;
  float stot = combS[0][hh] + combS[1][hh] + combS[2][hh] + combS[3][hh];
  float o = atot / (stot + 1e-16f) + bias[t];
  o = fmaxf(o, 0.f);
  outB[i * 256 + t] = f2bf(o);
  if (outF) outF[i * 256 + t] = o;
}

// ---------- flash attention: 512 thr, 256q/block, SINGLE-buffered K/V (48KB LDS -> 3 blocks/CU) ----------
// launch_bounds (512,4): VGPR cap 128 (kernel needs ~80; (512,6)'s cap 85 caused spills -> R12 regression).
// SPLITS=12 (uneven: splits 0-3 get 6 KV-tiles, 4-11 get 5) -> grid 768 = 3 blocks/CU resident.
// Q is prescaled by 0.125*log2(e) in the QKV GEMM epilogue -> P = exp2(S') = exp(S/8).
__global__ __launch_bounds__(512, 4) void attn_kernel(const unsigned short* __restrict__ qb, const unsigned short* __restrict__ kb,
                                                      const unsigned short* __restrict__ vt,
                                                      _Float16* __restrict__ Opart, float* __restrict__ Ol){
  __shared__ unsigned short K_lds[4096];      // [kv][dk], chunk ^ ((kv>>1)&7)
  __shared__ unsigned short V_lds[4096];      // [d][kv],  chunk ^ (d&7)
  __shared__ unsigned short P_lds[8][2048];   // per wave [32 q][64 kv], chunk ^ (q&7)
  const int t = threadIdx.x, lane = t & 63, w = t >> 6;
  const int c16 = lane & 15, g = lane >> 4;
  const int h = blockIdx.y, bq = blockIdx.x, sp = blockIdx.z;

  const int ntiles = (sp < 4) ? 6 : 5;
  const int tile0  = (sp < 4) ? sp * 6 : 24 + (sp - 4) * 5;
  const int kv_lo  = tile0 * 64;

  const int sr = t >> 3, sc = (t & 7) * 8;
  const int kw = sr * 64 + (((t & 7) ^ ((sr >> 1) & 7)) * 8);
  const int vw = sr * 64 + (((t & 7) ^ (sr & 7)) * 8);

  short8_t qa[2][2];
  #pragma unroll
  for (int qm = 0; qm < 2; qm++){
    int qrow = bq * 256 + w * 32 + qm * 16 + c16;
    union { uint4 u; short8_t s; } cv0, cv1;
    cv0.u = *(const uint4*)&qb[(size_t)qrow * 256 + h * 64 + g * 8];
    cv1.u = *(const uint4*)&qb[(size_t)qrow * 256 + h * 64 + 32 + g * 8];
    qa[qm][0] = cv0.s; qa[qm][1] = cv1.s;
  }

  f32x4_t oacc[2][4] = {};       // O^T[d = fn*16+g*4+r][q = qm*16+c16]
  float lsum[2] = {0.f, 0.f};

  {
    uint4 k0 = *(const uint4*)&kb[(size_t)(kv_lo + sr) * 256 + h * 64 + sc];
    uint4 v0 = *(const uint4*)&vt[(size_t)(h * 64 + sr) * 4096 + kv_lo + sc];
    *(uint4*)&K_lds[kw] = k0;
    *(uint4*)&V_lds[vw] = v0;
  }

  for (int ti = 0; ti < ntiles; ti++){
    const bool pf = (ti + 1) < ntiles;
    uint4 nk, nv;
    if (pf){
      int kvn = kv_lo + (ti + 1) * 64;
      nk = *(const uint4*)&kb[(size_t)(kvn + sr) * 256 + h * 64 + sc];
      nv = *(const uint4*)&vt[(size_t)(h * 64 + sr) * 4096 + kvn + sc];
    }
    wg_barrier();      // tile ti's LDS writes visible; vmcnt prefetch stays in flight
    unsigned short* Pw = P_lds[w];

    // S^T = K Q^T : lane holds S[q = qm*16+c16][kv = fn*16+g*4+r]
    f32x4_t sacc[2][4] = {};
    #pragma unroll
    for (int kd = 0; kd < 2; kd++){
      #pragma unroll
      for (int fn = 0; fn < 4; fn++){
        union { uint4 u; short8_t s; } kf;
        kf.u = *(const uint4*)&K_lds[(fn * 16 + c16) * 64 + (((kd * 4 + g) ^ ((c16 >> 1) & 7)) * 8)];
        sacc[0][fn] = __builtin_amdgcn_mfma_f32_16x16x32_bf16(kf.s, qa[0][kd], sacc[0][fn], 0, 0, 0);
        sacc[1][fn] = __builtin_amdgcn_mfma_f32_16x16x32_bf16(kf.s, qa[1][kd], sacc[1][fn], 0, 0, 0);
      }
    }

    // softmax without max-subtraction; P = 2^S' (Q carries 0.125*log2e)
    #pragma unroll
    for (int qm = 0; qm < 2; qm++){
      float ps = 0.f;
      int row = qm * 16 + c16;
      #pragma unroll
      for (int fn = 0; fn < 4; fn++){
        float p0 = __builtin_exp2f(sacc[qm][fn][0]);
        float p1 = __builtin_exp2f(sacc[qm][fn][1]);
        float p2 = __builtin_exp2f(sacc[qm][fn][2]);
        float p3 = __builtin_exp2f(sacc[qm][fn][3]);
        ps += (p0 + p1) + (p2 + p3);
        uint2 pk;
        pk.x = cvtpk_bf16(p0, p1);
        pk.y = cvtpk_bf16(p2, p3);
        int chunk = (fn * 2 + (g >> 1)) ^ (c16 & 7);
        *(uint2*)&Pw[row * 64 + chunk * 8 + (g & 1) * 4] = pk;
      }
      ps += __shfl_xor(ps, 16, 64);
      ps += __shfl_xor(ps, 32, 64);
      lsum[qm] += ps;
    }

    // O^T += V^T P^T (K=32 MFMA, b128 LDS reads)
    #pragma unroll
    for (int kd2 = 0; kd2 < 2; kd2++){
      const int ch = (((kd2 * 4 + g) ^ (c16 & 7)) * 8);
      union { uint4 u; short8_t s; } pt0, pt1;
      pt0.u = *(const uint4*)&Pw[c16 * 64 + ch];
      pt1.u = *(const uint4*)&Pw[(16 + c16) * 64 + ch];
      #pragma unroll
      for (int fn = 0; fn < 4; fn++){
        union { uint4 u; short8_t s; } vf;
        vf.u = *(const uint4*)&V_lds[(fn * 16 + c16) * 64 + ch];
        oacc[0][fn] = __builtin_amdgcn_mfma_f32_16x16x32_bf16(vf.s, pt0.s, oacc[0][fn], 0, 0, 0);
        oacc[1][fn] = __builtin_amdgcn_mfma_f32_16x16x32_bf16(vf.s, pt1.s, oacc[1][fn], 0, 0, 0);
      }
    }

    if (pf){
      wg_barrier();    // all reads of tile ti done before overwrite
      *(uint4*)&K_lds[kw] = nk;
      *(uint4*)&V_lds[vw] = nv;
    }
  }

  // f16 partials (bf16 fails: cancellation-amplified, R5; f16 mantissa is 8x finer)
  const int sh = sp * 4 + h;
  #pragma unroll
  for (int qm = 0; qm < 2; qm++){
    int node = bq * 256 + w * 32 + qm * 16 + c16;
    #pragma unroll
    for (int fn = 0; fn < 4; fn++){
      union { _Float16 h[4]; uint2 q; } pk;
      #pragma unroll
      for (int r = 0; r < 4; r++) pk.h[r] = (_Float16)oacc[qm][fn][r];
      *(uint2*)&Opart[((size_t)sh * N_NODES + node) * 64 + fn * 16 + g * 4] = pk.q;
    }
    if (g == 0) Ol[(size_t)sh * N_NODES + node] = lsum[qm];
  }
}

// ---------- Wo GEMM + split-K combine (f16 partials) + residual + LN + classifier, fused ----------
__global__ __launch_bounds__(256) void wo_ln_cls_kernel(const _Float16* __restrict__ Opart, const float* __restrict__ Ol,
                                                        const unsigned short* __restrict__ Wt, const float* __restrict__ bo,
                                                        const float* __restrict__ h2f, const float* __restrict__ gg,
                                                        const float* __restrict__ bb,
                                                        const unsigned short* __restrict__ Wt1, const float* __restrict__ b1,
                                                        const float* __restrict__ w2, const float* __restrict__ b2,
                                                        float* __restrict__ out){
  __shared__ unsigned short Ab[2][512];
  __shared__ unsigned short Bb[2][8192];
  __shared__ unsigned short Cb[2][4096];
  __shared__ unsigned short hl[16 * 264];    // LN output tile, pad 8
  __shared__ float red1[4][16], red2[4][16];
  __shared__ float cred0[4][16], cred1[4][16];
  __shared__ float Ls[64];     // 1/L for [node16][head4]
  const int t = threadIdx.x, lane = t & 63, w = t >> 6;
  const int c16 = lane & 15, g = lane >> 4;
  const int bm = blockIdx.x;

  const int arow = t >> 2, achk = t & 3;
  const int aswz = arow * 32 + ((achk ^ ((arow >> 1) & 3)) * 8);
  const int bq_ = t >> 2, bchk = t & 3;

  if (t < 64){
    int node = bm * 16 + (t >> 2), h = t & 3;
    float L = 0.f;
    #pragma unroll
    for (int s = 0; s < SPLITS; s++) L += Ol[(size_t)(s * 4 + h) * N_NODES + node];
    Ls[t] = 1.f / L;
  }
  __syncthreads();

  const int afr = c16 * 32 + ((g ^ ((c16 >> 1) & 3)) * 8);
  int bfr[4];
  #pragma unroll
  for (int fn = 0; fn < 4; fn++){
    int col = w * 64 + fn * 16 + c16;
    bfr[fn] = col * 32 + ((g ^ ((col >> 1) & 3)) * 8);
  }

  const int anode = bm * 16 + arow;
  auto combineA = [&](int k0) -> uint4 {
    int c0 = k0 + achk * 8;
    int hh = c0 >> 6, d0 = c0 & 63;
    float a[8] = {0.f,0.f,0.f,0.f,0.f,0.f,0.f,0.f};
    #pragma unroll
    for (int s = 0; s < SPLITS; s++){
      union { uint4 q; _Float16 h[8]; } u;
      u.q = *(const uint4*)&Opart[((size_t)(s * 4 + hh) * N_NODES + anode) * 64 + d0];
      #pragma unroll
      for (int j = 0; j < 8; j++) a[j] += (float)u.h[j];
    }
    float Li = Ls[(arow << 2) | hh];
    union { unsigned short u[8]; uint4 q; } o;
    #pragma unroll
    for (int j = 0; j < 8; j++) o.u[j] = f2bf(a[j] * Li);
    return o.q;
  };

  f32x4_t acc[4] = {};
  {
    if (t < 64) *(uint4*)&Ab[0][aswz] = combineA(0);
    #pragma unroll
    for (int j = 0; j < 4; j++){
      int col = j * 64 + bq_;
      *(uint4*)&Bb[0][col * 32 + ((bchk ^ ((col >> 1) & 3)) * 8)] = *(const uint4*)&Wt[(size_t)col * 256 + bchk * 8];
    }
  }
  int cur = 0;
  for (int i = 0; i < 8; i++){
    const bool pf = i < 7;
    uint4 pb[4];
    uint4 av;
    int k1 = (i + 1) * 32;
    if (pf){
      if (t < 64) av = combineA(k1);
      #pragma unroll
      for (int j = 0; j < 4; j++){
        int col = j * 64 + bq_;
        pb[j] = *(const uint4*)&Wt[(size_t)col * 256 + k1 + bchk * 8];
      }
    }
    wg_barrier();
    union { uint4 u; short8_t s; } a, b;
    a.u = *(const uint4*)&Ab[cur][afr];
    #pragma unroll
    for (int fn = 0; fn < 4; fn++){
      b.u = *(const uint4*)&Bb[cur][bfr[fn]];
      acc[fn] = __builtin_amdgcn_mfma_f32_16x16x32_bf16(a.s, b.s, acc[fn], 0, 0, 0);
    }
    if (pf){
      if (t < 64) *(uint4*)&Ab[cur ^ 1][aswz] = av;
      #pragma unroll
      for (int j = 0; j < 4; j++){
        int col = j * 64 + bq_;
        *(uint4*)&Bb[cur ^ 1][col * 32 + ((bchk ^ ((col >> 1) & 3)) * 8)] = pb[j];
      }
      cur ^= 1;
    }
  }

  // epilogue: bias + residual, register-space LN, result -> LDS tile hl
  float vv[4][4];
  #pragma unroll
  for (int fn = 0; fn < 4; fn++){
    int col = w * 64 + fn * 16 + c16;
    float bia = bo[col];
    #pragma unroll
    for (int r = 0; r < 4; r++)
      vv[fn][r] = acc[fn][r] + bia + h2f[(size_t)(bm * 16 + g * 4 + r) * 256 + col];
  }
  #pragma unroll
  for (int r = 0; r < 4; r++){
    float a = 0.f, b = 0.f;
    #pragma unroll
    for (int fn = 0; fn < 4; fn++){ a += vv[fn][r]; b += vv[fn][r] * vv[fn][r]; }
    a = rowsum16(a); b = rowsum16(b);
    if (c16 == 0){ red1[w][g * 4 + r] = a; red2[w][g * 4 + r] = b; }
  }
  __syncthreads();
  #pragma unroll
  for (int r = 0; r < 4; r++){
    int row = g * 4 + r;
    float S1 = red1[0][row] + red1[1][row] + red1[2][row] + red1[3][row];
    float S2 = red2[0][row] + red2[1][row] + red2[2][row] + red2[3][row];
    float mean = S1 * (1.f / 256.f);
    float var = S2 * (1.f / 256.f) - mean * mean;
    float rs = rsqrtf(var + 1e-5f);
    #pragma unroll
    for (int fn = 0; fn < 4; fn++){
      int col = w * 64 + fn * 16 + c16;
      hl[row * 264 + col] = f2bf((vv[fn][r] - mean) * rs * gg[col] + bb[col]);
    }
  }

  // ---- classifier phase: c1 = relu(hl @ W1 + b1); out = c1 @ w2 + b2 ----
  wg_barrier();
  int cfr[2];
  #pragma unroll
  for (int fn = 0; fn < 2; fn++){
    int col = w * 32 + fn * 16 + c16;
    cfr[fn] = col * 32 + ((g ^ ((col >> 1) & 3)) * 8);
  }
  f32x4_t cacc[2] = {};
  {
    #pragma unroll
    for (int j = 0; j < 2; j++){
      int col = j * 64 + bq_;
      *(uint4*)&Cb[0][col * 32 + ((bchk ^ ((col >> 1) & 3)) * 8)] = *(const uint4*)&Wt1[(size_t)col * 256 + bchk * 8];
    }
  }
  cur = 0;
  for (int i = 0; i < 8; i++){
    const bool pf = i < 7;
    uint4 pb[2];
    if (pf){
      int k1 = (i + 1) * 32;
      #pragma unroll
      for (int j = 0; j < 2; j++){
        int col = j * 64 + bq_;
        pb[j] = *(const uint4*)&Wt1[(size_t)col * 256 + k1 + bchk * 8];
      }
    }
    wg_barrier();
    union { uint4 u; short8_t s; } a, b;
    a.u = *(const uint4*)&hl[c16 * 264 + i * 32 + g * 8];
    #pragma unroll
    for (int fn = 0; fn < 2; fn++){
      b.u = *(const uint4*)&Cb[cur][cfr[fn]];
      cacc[fn] = __builtin_amdgcn_mfma_f32_16x16x32_bf16(a.s, b.s, cacc[fn], 0, 0, 0);
    }
    if (pf){
      #pragma unroll
      for (int j = 0; j < 2; j++){
        int col = j * 64 + bq_;
        *(uint4*)&Cb[cur ^ 1][col * 32 + ((bchk ^ ((col >> 1) & 3)) * 8)] = pb[j];
      }
      cur ^= 1;
    }
  }
  float cv[2][4];
  #pragma unroll
  for (int fn = 0; fn < 2; fn++){
    int col = w * 32 + fn * 16 + c16;
    float bia = b1[col];
    #pragma unroll
    for (int r = 0; r < 4; r++) cv[fn][r] = fmaxf(cacc[fn][r] + bia, 0.f);
  }
  float w20 = w2[(w * 32 + c16) * 2],      w21 = w2[(w * 32 + c16) * 2 + 1];
  float w30 = w2[(w * 32 + 16 + c16) * 2], w31 = w2[(w * 32 + 16 + c16) * 2 + 1];
  #pragma unroll
  for (int r = 0; r < 4; r++){
    float a0 = cv[0][r] * w20 + cv[1][r] * w30;
    float a1 = cv[0][r] * w21 + cv[1][r] * w31;
    a0 = rowsum16(a0); a1 = rowsum16(a1);
    if (c16 == 0){ cred0[w][g * 4 + r] = a0; cred1[w][g * 4 + r] = a1; }
  }
  __syncthreads();
  if (t < 16){
    float q0 = cred0[0][t] + cred0[1][t] + cred0[2][t] + cred0[3][t] + b2[0];
    float q1 = cred1[0][t] + cred1[1][t] + cred1[2][t] + cred1[3][t] + b2[1];
    out[(size_t)(bm * 16 + t) * 2]     = q0;
    out[(size_t)(bm * 16 + t) * 2 + 1] = q1;
  }
}

// ---------- host ----------
extern "C" void kernel_launch(void* const* d_in, const int* in_sizes, int n_in,
                              void* d_out, int out_size, void* d_ws, size_t ws_size,
                              hipStream_t stream){
  const float* x      = (const float*)d_in[0];
  const int*   ei     = (const int*)d_in[1];
  const float* emb_w  = (const float*)d_in[2];
  const float* emb_b  = (const float*)d_in[3];
  const float* g1_wl  = (const float*)d_in[4];
  const float* g1_wr  = (const float*)d_in[5];
  const float* g1_att = (const float*)d_in[6];
  const float* g1_b   = (const float*)d_in[7];
  const float* g2_wl  = (const float*)d_in[8];
  const float* g2_wr  = (const float*)d_in[9];
  const float* g2_att = (const float*)d_in[10];
  const float* g2_b   = (const float*)d_in[11];
  const float* wq     = (const float*)d_in[12];
  const float* wk     = (const float*)d_in[13];
  const float* wv     = (const float*)d_in[14];
  const float* bq     = (const float*)d_in[15];
  const float* bk     = (const float*)d_in[16];
  const float* bv     = (const float*)d_in[17];
  const float* wo     = (const float*)d_in[18];
  const float* bo     = (const float*)d_in[19];
  const float* ln_g   = (const float*)d_in[20];
  const float* ln_b   = (const float*)d_in[21];
  const float* cls_w1 = (const float*)d_in[22];
  const float* cls_b1 = (const float*)d_in[23];
  const float* cls_w2 = (const float*)d_in[24];
  const float* cls_b2 = (const float*)d_in[25];
  float* out = (float*)d_out;

  char* wsb = (char*)d_ws;
  size_t o = 0;
  auto take = [&](size_t bytes) -> char* {
    char* r = wsb + o; o += (bytes + 255) & ~(size_t)255; return r;
  };
  unsigned short* wt_emb  = (unsigned short*)take(768 * 256 * 2);
  unsigned short* wt_wl1  = (unsigned short*)take(256 * 256 * 2);
  unsigned short* wt_wr1  = (unsigned short*)take(256 * 256 * 2);
  unsigned short* wt_wl2  = (unsigned short*)take(256 * 256 * 2);
  unsigned short* wt_wr2  = (unsigned short*)take(256 * 256 * 2);
  unsigned short* wt_wq   = (unsigned short*)take(256 * 256 * 2);
  unsigned short* wt_wk   = (unsigned short*)take(256 * 256 * 2);
  unsigned short* wt_wv   = (unsigned short*)take(256 * 256 * 2);
  unsigned short* wt_wo   = (unsigned short*)take(256 * 256 * 2);
  unsigned short* wt_cls1 = (unsigned short*)take(256 * 128 * 2);
  unsigned short* x_bf    = (unsigned short*)take((size_t)4096 * 768 * 2);
  unsigned short* h0_bf   = (unsigned short*)take((size_t)4096 * 256 * 2);
  unsigned short* xs1_bf  = (unsigned short*)take((size_t)4096 * 256 * 2);
  unsigned short* xd1_bf  = (unsigned short*)take((size_t)4096 * 256 * 2);
  unsigned short* h1_bf   = (unsigned short*)take((size_t)4096 * 256 * 2);
  unsigned short* xs2_bf  = (unsigned short*)take((size_t)4096 * 256 * 2);
  unsigned short* xd2_bf  = (unsigned short*)take((size_t)4096 * 256 * 2);
  unsigned short* h2_bf   = (unsigned short*)take((size_t)4096 * 256 * 2);
  float*          h2_f    = (float*)take((size_t)4096 * 256 * 4);
  unsigned short* q_bf    = (unsigned short*)take((size_t)4096 * 256 * 2);
  unsigned short* k_bf    = (unsigned short*)take((size_t)4096 * 256 * 2);
  unsigned short* vt_bf   = (unsigned short*)take((size_t)4096 * 256 * 2);
  int* cnt  = (int*)take(4096 * 4);
  int* csrc = (int*)take((size_t)N_NODES * BUCKET_CAP * 4);
  _Float16* Opart = (_Float16*)take((size_t)SPLITS * 4 * N_NODES * 64 * 2);
  float*    Ol    = (float*)take((size_t)SPLITS * 4 * N_NODES * 4);

  // prep: x convert + weight transposes + zero cnt
  TJobs TJ;
  TJob tj[10] = {
    { emb_w,  wt_emb,  768, 256, 0 },
    { g1_wl,  wt_wl1,  256, 256, 0 },
    { g1_wr,  wt_wr1,  256, 256, 0 },
    { g2_wl,  wt_wl2,  256, 256, 0 },
    { g2_wr,  wt_wr2,  256, 256, 0 },
    { wq,     wt_wq,   256, 256, 0 },
    { wk,     wt_wk,   256, 256, 0 },
    { wv,     wt_wv,   256, 256, 0 },
    { wo,     wt_wo,   256, 256, 0 },
    { cls_w1, wt_cls1, 256, 128, 0 },
  };
  int tb = 0;
  for (int i = 0; i < 10; i++){
    tj[i].tile0 = tb;
    tb += (tj[i].rows >> 6) * (tj[i].cols >> 6);
    TJ.j[i] = tj[i];
  }
  prep_kernel<<<3072 + tb + 16, 256, 0, stream>>>(x, x_bf, TJ, tb, cnt);

  // bucket scatter (no CSR)
  scatter_kernel<<<(E_TOTAL + 255) / 256, 256, 0, stream>>>(ei, cnt, csrc);

  GJobs J;
  // embedding GEMM
  J = {}; J.j[0] = { wt_emb, emb_b, nullptr, h0_bf, nullptr, 1.f };
  gemm_kernel<<<dim3(64, 4, 1), 256, 0, stream>>>(x_bf, J, 768, 256, 0);
  // GAT1
  J = {}; J.j[0] = { wt_wl1, nullptr, nullptr, xs1_bf, nullptr, 1.f }; J.j[1] = { wt_wr1, nullptr, nullptr, xd1_bf, nullptr, 1.f };
  gemm_kernel<<<dim3(64, 4, 2), 256, 0, stream>>>(h0_bf, J, 256, 256, 0);
  gat_gather<<<4096, 256, 0, stream>>>(xs1_bf, xd1_bf, g1_att, g1_b, cnt, csrc, h1_bf, nullptr);
  // GAT2
  J = {}; J.j[0] = { wt_wl2, nullptr, nullptr, xs2_bf, nullptr, 1.f }; J.j[1] = { wt_wr2, nullptr, nullptr, xd2_bf, nullptr, 1.f };
  gemm_kernel<<<dim3(64, 4, 2), 256, 0, stream>>>(h1_bf, J, 256, 256, 0);
  gat_gather<<<4096, 256, 0, stream>>>(xs2_bf, xd2_bf, g2_att, g2_b, cnt, csrc, h2_bf, h2_f);
  // QKV (Q prescaled by 0.125*log2e for exp2-softmax; V written transposed via outT)
  J = {};
  J.j[0] = { wt_wq, bq, nullptr, q_bf, nullptr, 0.125f * 1.44269504f };
  J.j[1] = { wt_wk, bk, nullptr, k_bf, nullptr, 1.f };
  J.j[2] = { wt_wv, bv, nullptr, nullptr, vt_bf, 1.f };
  gemm_kernel<<<dim3(64, 4, 3), 256, 0, stream>>>(h2_bf, J, 256, 256, 0);
  // attention (f16 partials, SPLITS=12, 48KB LDS -> 3 blocks/CU, VGPR cap 128)
  attn_kernel<<<dim3(16, 4, SPLITS), 512, 0, stream>>>(q_bf, k_bf, vt_bf, Opart, Ol);
  // Wo + combine + residual + LN + classifier
  wo_ln_cls_kernel<<<256, 256, 0, stream>>>(Opart, Ol, wt_wo, bo, h2_f, ln_g, ln_b,
                                            wt_cls1, cls_b1, cls_w2, cls_b2, out);

  (void)in_sizes; (void)n_in; (void)out_size; (void)ws_size;
}

// Round 14
// 146.673 us; speedup vs baseline: 1.6005x; 1.0245x over previous
//
#include <hip/hip_runtime.h>

typedef __attribute__((ext_vector_type(8))) short short8_t;
typedef __attribute__((ext_vector_type(4))) float f32x4_t;

#define N_NODES  4096
#define E0_EDGES 262144
#define E_TOTAL  266240
#define SPLITS   12
#define BUCKET_CAP 160                     // Poisson(65) degree; P(deg>=160) ~ 1e-21

// ---------- helpers ----------
__device__ __forceinline__ float bf2f(unsigned short u){
  union { unsigned int i; float f; } v; v.i = ((unsigned int)u) << 16; return v.f;
}
__device__ __forceinline__ unsigned short f2bf(float f){
  union { float f; unsigned int i; } v; v.f = f;
  unsigned int r = (v.i + 0x7FFFu + ((v.i >> 16) & 1u)) >> 16;
  return (unsigned short)r;
}
__device__ __forceinline__ unsigned int cvtpk_bf16(float lo, float hi){
  unsigned int r;
  asm volatile("v_cvt_pk_bf16_f32 %0, %1, %2" : "=v"(r) : "v"(lo), "v"(hi));
  return r;
}
template<int CTRL>
__device__ __forceinline__ float dpp_add(float x){
  int v = __builtin_amdgcn_update_dpp(0, __float_as_int(x), CTRL, 0xF, 0xF, true);
  return x + __int_as_float(v);
}
__device__ __forceinline__ float rowsum16(float x){
  x = dpp_add<0xB1>(x); x = dpp_add<0x4E>(x); x = dpp_add<0x124>(x); x = dpp_add<0x128>(x);
  return x;
}
// raw barrier: drains LDS ops only; prefetched global loads stay in flight
__device__ __forceinline__ void wg_barrier(){
  asm volatile("s_waitcnt lgkmcnt(0)" ::: "memory");
  __builtin_amdgcn_s_barrier();
  asm volatile("" ::: "memory");
}
__device__ __forceinline__ uint4 cvt8_f32_to_bf16(float4 f0, float4 f1){
  union { unsigned short u[8]; uint4 q; } o;
  o.u[0]=f2bf(f0.x); o.u[1]=f2bf(f0.y); o.u[2]=f2bf(f0.z); o.u[3]=f2bf(f0.w);
  o.u[4]=f2bf(f1.x); o.u[5]=f2bf(f1.y); o.u[6]=f2bf(f1.z); o.u[7]=f2bf(f1.w);
  return o.q;
}

// ---------- prep: x convert + weight transpose-convert + zero cnt ----------
struct TJob { const float* src; unsigned short* dst; int rows, cols, tile0; };
struct TJobs { TJob j[10]; };

__global__ __launch_bounds__(256) void prep_kernel(const float* __restrict__ x, unsigned short* __restrict__ xb,
                                                   TJobs jobs, int tb, int* __restrict__ zp){
  __shared__ unsigned short tile[64 * 64];
  int b = blockIdx.x, t = threadIdx.x;
  if (b < 3072){
    int i = (b * 256 + t) * 4;
    float4 v = *(const float4*)&x[i];
    union { unsigned short u[4]; uint2 q; } o;
    o.u[0] = f2bf(v.x); o.u[1] = f2bf(v.y); o.u[2] = f2bf(v.z); o.u[3] = f2bf(v.w);
    *(uint2*)&xb[i] = o.q;
    return;
  }
  if (b < 3072 + tb){
    int bb = b - 3072;
    int ji = 0;
    #pragma unroll
    for (int k = 1; k < 10; k++) if (bb >= jobs.j[k].tile0) ji = k;
    TJob J = jobs.j[ji];
    int lt = bb - J.tile0;
    int tpr = J.cols >> 6;
    int tr = lt / tpr, tc = lt - tr * tpr;
    #pragma unroll
    for (int i2 = 0; i2 < 2; i2++){
      int e = i2 * 2048 + t * 8;
      int nl = e >> 6, c8 = e & 63;
      const float* sp = &J.src[(size_t)(tr * 64 + nl) * J.cols + tc * 64 + c8];
      float4 v0 = *(const float4*)sp;
      float4 v1 = *(const float4*)(sp + 4);
      *(uint4*)&tile[nl * 64 + (((c8 >> 3) ^ ((nl >> 3) & 7)) * 8)] = cvt8_f32_to_bf16(v0, v1);
    }
    __syncthreads();
    #pragma unroll
    for (int i2 = 0; i2 < 2; i2++){
      int e = i2 * 2048 + t * 8;
      int cl = e >> 6, n8 = e & 63;
      union { unsigned short u[8]; uint4 q; } o;
      #pragma unroll
      for (int j = 0; j < 8; j++){
        int row = n8 + j;
        o.u[j] = tile[row * 64 + (((cl >> 3) ^ ((row >> 3) & 7)) * 8) + (cl & 7)];
      }
      *(uint4*)&J.dst[(size_t)(tc * 64 + cl) * J.rows + tr * 64 + n8] = o.q;
    }
    return;
  }
  int i = (b - 3072 - tb) * 256 + t;
  if (i < N_NODES) zp[i] = 0;
}

// ---------- bucket scatter: no CSR, fixed-capacity per-node buckets ----------
__global__ __launch_bounds__(256) void scatter_kernel(const int* __restrict__ ei, int* __restrict__ cnt,
                                                      int* __restrict__ csrc){
  int e = blockIdx.x * 256 + threadIdx.x;
  if (e >= E_TOTAL) return;
  int s, d;
  if (e < E0_EDGES){ s = ei[e]; d = ei[E0_EDGES + e]; }
  else { s = d = e - E0_EDGES; }
  int pos = atomicAdd(&cnt[d], 1);
  csrc[d * BUCKET_CAP + pos] = s;
}

// ---------- generic bf16 MFMA GEMM (double-buffered, BK=64 as two 32-K sub-tiles) ----------
struct GJob { const unsigned short* Wt; const float* bias; float* outF; unsigned short* outB; unsigned short* outT; float scale; };
struct GJobs { GJob j[3]; };

__global__ __launch_bounds__(256) void gemm_kernel(const unsigned short* __restrict__ A, GJobs jobs,
                                                   int K, int Nc, int relu){
  // layout per buffer: A half0 [0,2048), A half1 [2048,4096), B half0 [4096,6144), B half1 [6144,8192)
  __shared__ unsigned short lds[16384];   // 2 buffers
  const int t = threadIdx.x;
  const GJob job = jobs.j[blockIdx.z];
  const int lane = t & 63, w = t >> 6;
  const int wm = w >> 1, wn = w & 1;
  const int c16 = lane & 15, g = lane >> 4;
  const int bm = blockIdx.x, bn = blockIdx.y;

  const int srow = t >> 2, schunk = t & 3;
  const unsigned short* Ag = A      + (size_t)(bm * 64 + srow) * K + schunk * 8;
  const unsigned short* Bg = job.Wt + (size_t)(bn * 64 + srow) * K + schunk * 8;
  const int swz = srow * 32 + ((schunk ^ ((srow >> 1) & 3)) * 8);

  const int arow0 = wm * 32 + c16, arow1 = arow0 + 16;
  const int aoff0 = arow0 * 32 + ((g ^ ((arow0 >> 1) & 3)) * 8);
  const int aoff1 = arow1 * 32 + ((g ^ ((arow1 >> 1) & 3)) * 8);
  const int bcol0 = wn * 32 + c16, bcol1 = bcol0 + 16;
  const int boff0 = 4096 + bcol0 * 32 + ((g ^ ((bcol0 >> 1) & 3)) * 8);
  const int boff1 = 4096 + bcol1 * 32 + ((g ^ ((bcol1 >> 1) & 3)) * 8);

  f32x4_t acc[2][2] = {};
  const int nk = K >> 6;   // BK=64 steps

  {
    uint4 a0 = *(const uint4*)(Ag);
    uint4 a1 = *(const uint4*)(Ag + 32);
    uint4 b0 = *(const uint4*)(Bg);
    uint4 b1 = *(const uint4*)(Bg + 32);
    *(uint4*)&lds[swz]        = a0;
    *(uint4*)&lds[2048 + swz] = a1;
    *(uint4*)&lds[4096 + swz] = b0;
    *(uint4*)&lds[6144 + swz] = b1;
  }
  int cur = 0;
  for (int i = 0; i < nk; i++){
    const bool pf = (i + 1) < nk;
    uint4 pa0, pa1, pb0, pb1;
    if (pf){
      int k1 = (i + 1) * 64;
      pa0 = *(const uint4*)(Ag + k1);
      pa1 = *(const uint4*)(Ag + k1 + 32);
      pb0 = *(const uint4*)(Bg + k1);
      pb1 = *(const uint4*)(Bg + k1 + 32);
    }
    wg_barrier();
    const int base = cur * 8192;
    #pragma unroll
    for (int hk = 0; hk < 2; hk++){
      const int hb = base + hk * 2048;
      union { uint4 u; short8_t s; } a0, a1, b0, b1;
      a0.u = *(const uint4*)&lds[hb + aoff0];
      a1.u = *(const uint4*)&lds[hb + aoff1];
      b0.u = *(const uint4*)&lds[hb + boff0];
      b1.u = *(const uint4*)&lds[hb + boff1];
      acc[0][0] = __builtin_amdgcn_mfma_f32_16x16x32_bf16(a0.s, b0.s, acc[0][0], 0, 0, 0);
      acc[0][1] = __builtin_amdgcn_mfma_f32_16x16x32_bf16(a0.s, b1.s, acc[0][1], 0, 0, 0);
      acc[1][0] = __builtin_amdgcn_mfma_f32_16x16x32_bf16(a1.s, b0.s, acc[1][0], 0, 0, 0);
      acc[1][1] = __builtin_amdgcn_mfma_f32_16x16x32_bf16(a1.s, b1.s, acc[1][1], 0, 0, 0);
    }
    if (pf){
      const int nb = (cur ^ 1) * 8192;
      *(uint4*)&lds[nb + swz]        = pa0;
      *(uint4*)&lds[nb + 2048 + swz] = pa1;
      *(uint4*)&lds[nb + 4096 + swz] = pb0;
      *(uint4*)&lds[nb + 6144 + swz] = pb1;
      cur ^= 1;
    }
  }

  #pragma unroll
  for (int fm = 0; fm < 2; fm++){
    #pragma unroll
    for (int fn = 0; fn < 2; fn++){
      int col = bn * 64 + wn * 32 + fn * 16 + c16;
      float bia = job.bias ? job.bias[col] : 0.f;
      float vv[4];
      #pragma unroll
      for (int r = 0; r < 4; r++){
        float v = (acc[fm][fn][r] + bia) * job.scale;
        if (relu) v = fmaxf(v, 0.f);
        vv[r] = v;
      }
      int row0 = bm * 64 + wm * 32 + fm * 16 + g * 4;
      if (job.outF){
        #pragma unroll
        for (int r = 0; r < 4; r++) job.outF[(size_t)(row0 + r) * Nc + col] = vv[r];
      }
      if (job.outB){
        #pragma unroll
        for (int r = 0; r < 4; r++) job.outB[(size_t)(row0 + r) * Nc + col] = f2bf(vv[r]);
      }
      if (job.outT){
        union { unsigned short u[4]; uint2 q; } pk;
        #pragma unroll
        for (int r = 0; r < 4; r++) pk.u[r] = f2bf(vv[r]);
        *(uint2*)&job.outT[(size_t)col * 4096 + row0] = pk.q;
      }
    }
  }
}

// ---------- GATv2 gather: wave = one edge slot, 2x unrolled; bucket layout ----------
__global__ __launch_bounds__(256) void gat_gather(const unsigned short* __restrict__ xs, const unsigned short* __restrict__ xd,
                                                  const float* __restrict__ att, const float* __restrict__ bias,
                                                  const int* __restrict__ cnt, const int* __restrict__ csrc,
                                                  unsigned short* __restrict__ outB, float* __restrict__ outF){
  __shared__ float combL[4][256];
  __shared__ float combS[4][4];
  const int i = blockIdx.x, t = threadIdx.x;
  const int lane = t & 63, w = t >> 6;
  float xdc[4], attc[4];
  {
    uint2 xv = *(const uint2*)&xd[i * 256 + lane * 4];
    xdc[0] = bf2f((unsigned short)(xv.x & 0xffff)); xdc[1] = bf2f((unsigned short)(xv.x >> 16));
    xdc[2] = bf2f((unsigned short)(xv.y & 0xffff)); xdc[3] = bf2f((unsigned short)(xv.y >> 16));
    float4 av = *(const float4*)&att[lane * 4];
    attc[0] = av.x; attc[1] = av.y; attc[2] = av.z; attc[3] = av.w;
  }
  const int b1 = cnt[i];
  const int* bucket = csrc + i * BUCKET_CAP;
  float acc0 = 0.f, acc1 = 0.f, acc2 = 0.f, acc3 = 0.f, ssum = 0.f;
  int p = w;
  for (; p + 4 < b1; p += 8){
    int sA = bucket[p], sB = bucket[p + 4];
    uint2 xa = *(const uint2*)&xs[sA * 256 + lane * 4];
    uint2 xb = *(const uint2*)&xs[sB * 256 + lane * 4];
    float a0 = bf2f((unsigned short)(xa.x & 0xffff)), a1 = bf2f((unsigned short)(xa.x >> 16));
    float a2 = bf2f((unsigned short)(xa.y & 0xffff)), a3 = bf2f((unsigned short)(xa.y >> 16));
    float b0_ = bf2f((unsigned short)(xb.x & 0xffff)), b1_ = bf2f((unsigned short)(xb.x >> 16));
    float b2_ = bf2f((unsigned short)(xb.y & 0xffff)), b3_ = bf2f((unsigned short)(xb.y >> 16));
    float va0 = a0 + xdc[0]; va0 = (va0 > 0.f) ? va0 : 0.2f * va0;
    float va1 = a1 + xdc[1]; va1 = (va1 > 0.f) ? va1 : 0.2f * va1;
    float va2 = a2 + xdc[2]; va2 = (va2 > 0.f) ? va2 : 0.2f * va2;
    float va3 = a3 + xdc[3]; va3 = (va3 > 0.f) ? va3 : 0.2f * va3;
    float vb0 = b0_ + xdc[0]; vb0 = (vb0 > 0.f) ? vb0 : 0.2f * vb0;
    float vb1 = b1_ + xdc[1]; vb1 = (vb1 > 0.f) ? vb1 : 0.2f * vb1;
    float vb2 = b2_ + xdc[2]; vb2 = (vb2 > 0.f) ? vb2 : 0.2f * vb2;
    float vb3 = b3_ + xdc[3]; vb3 = (vb3 > 0.f) ? vb3 : 0.2f * vb3;
    float eA = rowsum16(va0 * attc[0] + va1 * attc[1] + va2 * attc[2] + va3 * attc[3]);
    float eB = rowsum16(vb0 * attc[0] + vb1 * attc[1] + vb2 * attc[2] + vb3 * attc[3]);
    float pA = __expf(eA), pB = __expf(eB);
    ssum += pA + pB;
    acc0 += pA * a0 + pB * b0_; acc1 += pA * a1 + pB * b1_;
    acc2 += pA * a2 + pB * b2_; acc3 += pA * a3 + pB * b3_;
  }
  if (p < b1){
    int s = bucket[p];
    uint2 xv = *(const uint2*)&xs[s * 256 + lane * 4];
    float x0 = bf2f((unsigned short)(xv.x & 0xffff)), x1 = bf2f((unsigned short)(xv.x >> 16));
    float x2 = bf2f((unsigned short)(xv.y & 0xffff)), x3 = bf2f((unsigned short)(xv.y >> 16));
    float v0 = x0 + xdc[0]; v0 = (v0 > 0.f) ? v0 : 0.2f * v0;
    float v1 = x1 + xdc[1]; v1 = (v1 > 0.f) ? v1 : 0.2f * v1;
    float v2 = x2 + xdc[2]; v2 = (v2 > 0.f) ? v2 : 0.2f * v2;
    float v3 = x3 + xdc[3]; v3 = (v3 > 0.f) ? v3 : 0.2f * v3;
    float e = rowsum16(v0 * attc[0] + v1 * attc[1] + v2 * attc[2] + v3 * attc[3]);
    float pe = __expf(e);
    ssum += pe;
    acc0 += pe * x0; acc1 += pe * x1; acc2 += pe * x2; acc3 += pe * x3;
  }
  combL[w][lane * 4 + 0] = acc0; combL[w][lane * 4 + 1] = acc1;
  combL[w][lane * 4 + 2] = acc2; combL[w][lane * 4 + 3] = acc3;
  if ((lane & 15) == 0) combS[w][lane >> 4] = ssum;
  __syncthreads();
  float atot = combL[0][t] + combL[1][t] + combL[2][t] + combL[3][t];
  int hh = t >> 6;
  float stot = combS[0][hh] + combS[1][hh] + combS[2][hh] + combS[3][hh];
  float o = atot / (stot + 1e-16f) + bias[t];
  o = fmaxf(o, 0.f);
  outB[i * 256 + t] = f2bf(o);
  if (outF) outF[i * 256 + t] = o;
}

// ---------- flash attention: 512 thr, 256q/block, SINGLE-buffered K/V (48KB LDS -> 3 blocks/CU) ----------
// launch_bounds (512,4): VGPR cap 128 (kernel needs ~80; (512,6)'s cap 85 caused spills -> R12 regression).
// SPLITS=12 (uneven: splits 0-3 get 6 KV-tiles, 4-11 get 5) -> grid 768 = 3 blocks/CU resident.
// Q is prescaled by 0.125*log2(e) in the QKV GEMM epilogue -> P = exp2(S') = exp(S/8).
__global__ __launch_bounds__(512, 4) void attn_kernel(const unsigned short* __restrict__ qb, const unsigned short* __restrict__ kb,
                                                      const unsigned short* __restrict__ vt,
                                                      _Float16* __restrict__ Opart, float* __restrict__ Ol){
  __shared__ unsigned short K_lds[4096];      // [kv][dk], chunk ^ ((kv>>1)&7)
  __shared__ unsigned short V_lds[4096];      // [d][kv],  chunk ^ (d&7)
  __shared__ unsigned short P_lds[8][2048];   // per wave [32 q][64 kv], chunk ^ (q&7)
  const int t = threadIdx.x, lane = t & 63, w = t >> 6;
  const int c16 = lane & 15, g = lane >> 4;
  const int h = blockIdx.y, bq = blockIdx.x, sp = blockIdx.z;

  const int ntiles = (sp < 4) ? 6 : 5;
  const int tile0  = (sp < 4) ? sp * 6 : 24 + (sp - 4) * 5;
  const int kv_lo  = tile0 * 64;

  const int sr = t >> 3, sc = (t & 7) * 8;
  const int kw = sr * 64 + (((t & 7) ^ ((sr >> 1) & 7)) * 8);
  const int vw = sr * 64 + (((t & 7) ^ (sr & 7)) * 8);

  short8_t qa[2][2];
  #pragma unroll
  for (int qm = 0; qm < 2; qm++){
    int qrow = bq * 256 + w * 32 + qm * 16 + c16;
    union { uint4 u; short8_t s; } cv0, cv1;
    cv0.u = *(const uint4*)&qb[(size_t)qrow * 256 + h * 64 + g * 8];
    cv1.u = *(const uint4*)&qb[(size_t)qrow * 256 + h * 64 + 32 + g * 8];
    qa[qm][0] = cv0.s; qa[qm][1] = cv1.s;
  }

  f32x4_t oacc[2][4] = {};       // O^T[d = fn*16+g*4+r][q = qm*16+c16]
  float lsum[2] = {0.f, 0.f};

  {
    uint4 k0 = *(const uint4*)&kb[(size_t)(kv_lo + sr) * 256 + h * 64 + sc];
    uint4 v0 = *(const uint4*)&vt[(size_t)(h * 64 + sr) * 4096 + kv_lo + sc];
    *(uint4*)&K_lds[kw] = k0;
    *(uint4*)&V_lds[vw] = v0;
  }

  for (int ti = 0; ti < ntiles; ti++){
    const bool pf = (ti + 1) < ntiles;
    uint4 nk, nv;
    if (pf){
      int kvn = kv_lo + (ti + 1) * 64;
      nk = *(const uint4*)&kb[(size_t)(kvn + sr) * 256 + h * 64 + sc];
      nv = *(const uint4*)&vt[(size_t)(h * 64 + sr) * 4096 + kvn + sc];
    }
    wg_barrier();      // tile ti's LDS writes visible; vmcnt prefetch stays in flight
    unsigned short* Pw = P_lds[w];

    // S^T = K Q^T : lane holds S[q = qm*16+c16][kv = fn*16+g*4+r]
    f32x4_t sacc[2][4] = {};
    #pragma unroll
    for (int kd = 0; kd < 2; kd++){
      #pragma unroll
      for (int fn = 0; fn < 4; fn++){
        union { uint4 u; short8_t s; } kf;
        kf.u = *(const uint4*)&K_lds[(fn * 16 + c16) * 64 + (((kd * 4 + g) ^ ((c16 >> 1) & 7)) * 8)];
        sacc[0][fn] = __builtin_amdgcn_mfma_f32_16x16x32_bf16(kf.s, qa[0][kd], sacc[0][fn], 0, 0, 0);
        sacc[1][fn] = __builtin_amdgcn_mfma_f32_16x16x32_bf16(kf.s, qa[1][kd], sacc[1][fn], 0, 0, 0);
      }
    }

    // softmax without max-subtraction; P = 2^S' (Q carries 0.125*log2e)
    #pragma unroll
    for (int qm = 0; qm < 2; qm++){
      float ps = 0.f;
      int row = qm * 16 + c16;
      #pragma unroll
      for (int fn = 0; fn < 4; fn++){
        float p0 = __builtin_exp2f(sacc[qm][fn][0]);
        float p1 = __builtin_exp2f(sacc[qm][fn][1]);
        float p2 = __builtin_exp2f(sacc[qm][fn][2]);
        float p3 = __builtin_exp2f(sacc[qm][fn][3]);
        ps += (p0 + p1) + (p2 + p3);
        uint2 pk;
        pk.x = cvtpk_bf16(p0, p1);
        pk.y = cvtpk_bf16(p2, p3);
        int chunk = (fn * 2 + (g >> 1)) ^ (c16 & 7);
        *(uint2*)&Pw[row * 64 + chunk * 8 + (g & 1) * 4] = pk;
      }
      ps += __shfl_xor(ps, 16, 64);
      ps += __shfl_xor(ps, 32, 64);
      lsum[qm] += ps;
    }

    // O^T += V^T P^T (K=32 MFMA, b128 LDS reads)
    #pragma unroll
    for (int kd2 = 0; kd2 < 2; kd2++){
      const int ch = (((kd2 * 4 + g) ^ (c16 & 7)) * 8);
      union { uint4 u; short8_t s; } pt0, pt1;
      pt0.u = *(const uint4*)&Pw[c16 * 64 + ch];
      pt1.u = *(const uint4*)&Pw[(16 + c16) * 64 + ch];
      #pragma unroll
      for (int fn = 0; fn < 4; fn++){
        union { uint4 u; short8_t s; } vf;
        vf.u = *(const uint4*)&V_lds[(fn * 16 + c16) * 64 + ch];
        oacc[0][fn] = __builtin_amdgcn_mfma_f32_16x16x32_bf16(vf.s, pt0.s, oacc[0][fn], 0, 0, 0);
        oacc[1][fn] = __builtin_amdgcn_mfma_f32_16x16x32_bf16(vf.s, pt1.s, oacc[1][fn], 0, 0, 0);
      }
    }

    if (pf){
      wg_barrier();    // all reads of tile ti done before overwrite
      *(uint4*)&K_lds[kw] = nk;
      *(uint4*)&V_lds[vw] = nv;
    }
  }

  // f16 partials (bf16 fails: cancellation-amplified, R5; f16 mantissa is 8x finer)
  const int sh = sp * 4 + h;
  #pragma unroll
  for (int qm = 0; qm < 2; qm++){
    int node = bq * 256 + w * 32 + qm * 16 + c16;
    #pragma unroll
    for (int fn = 0; fn < 4; fn++){
      union { _Float16 h[4]; uint2 q; } pk;
      #pragma unroll
      for (int r = 0; r < 4; r++) pk.h[r] = (_Float16)oacc[qm][fn][r];
      *(uint2*)&Opart[((size_t)sh * N_NODES + node) * 64 + fn * 16 + g * 4] = pk.q;
    }
    if (g == 0) Ol[(size_t)sh * N_NODES + node] = lsum[qm];
  }
}

// ---------- Wo GEMM + split-K combine (f16 partials) + residual + LN + classifier, fused ----------
__global__ __launch_bounds__(256) void wo_ln_cls_kernel(const _Float16* __restrict__ Opart, const float* __restrict__ Ol,
                                                        const unsigned short* __restrict__ Wt, const float* __restrict__ bo,
                                                        const float* __restrict__ h2f, const float* __restrict__ gg,
                                                        const float* __restrict__ bb,
                                                        const unsigned short* __restrict__ Wt1, const float* __restrict__ b1,
                                                        const float* __restrict__ w2, const float* __restrict__ b2,
                                                        float* __restrict__ out){
  __shared__ unsigned short Ab[2][512];
  __shared__ unsigned short Bb[2][8192];
  __shared__ unsigned short Cb[2][4096];
  __shared__ unsigned short hl[16 * 264];    // LN output tile, pad 8
  __shared__ float red1[4][16], red2[4][16];
  __shared__ float cred0[4][16], cred1[4][16];
  __shared__ float Ls[64];     // 1/L for [node16][head4]
  const int t = threadIdx.x, lane = t & 63, w = t >> 6;
  const int c16 = lane & 15, g = lane >> 4;
  const int bm = blockIdx.x;

  const int arow = t >> 2, achk = t & 3;
  const int aswz = arow * 32 + ((achk ^ ((arow >> 1) & 3)) * 8);
  const int bq_ = t >> 2, bchk = t & 3;

  if (t < 64){
    int node = bm * 16 + (t >> 2), h = t & 3;
    float L = 0.f;
    #pragma unroll
    for (int s = 0; s < SPLITS; s++) L += Ol[(size_t)(s * 4 + h) * N_NODES + node];
    Ls[t] = 1.f / L;
  }
  __syncthreads();

  const int afr = c16 * 32 + ((g ^ ((c16 >> 1) & 3)) * 8);
  int bfr[4];
  #pragma unroll
  for (int fn = 0; fn < 4; fn++){
    int col = w * 64 + fn * 16 + c16;
    bfr[fn] = col * 32 + ((g ^ ((col >> 1) & 3)) * 8);
  }

  const int anode = bm * 16 + arow;
  auto combineA = [&](int k0) -> uint4 {
    int c0 = k0 + achk * 8;
    int hh = c0 >> 6, d0 = c0 & 63;
    float a[8] = {0.f,0.f,0.f,0.f,0.f,0.f,0.f,0.f};
    #pragma unroll
    for (int s = 0; s < SPLITS; s++){
      union { uint4 q; _Float16 h[8]; } u;
      u.q = *(const uint4*)&Opart[((size_t)(s * 4 + hh) * N_NODES + anode) * 64 + d0];
      #pragma unroll
      for (int j = 0; j < 8; j++) a[j] += (float)u.h[j];
    }
    float Li = Ls[(arow << 2) | hh];
    union { unsigned short u[8]; uint4 q; } o;
    #pragma unroll
    for (int j = 0; j < 8; j++) o.u[j] = f2bf(a[j] * Li);
    return o.q;
  };

  f32x4_t acc[4] = {};
  {
    if (t < 64) *(uint4*)&Ab[0][aswz] = combineA(0);
    #pragma unroll
    for (int j = 0; j < 4; j++){
      int col = j * 64 + bq_;
      *(uint4*)&Bb[0][col * 32 + ((bchk ^ ((col >> 1) & 3)) * 8)] = *(const uint4*)&Wt[(size_t)col * 256 + bchk * 8];
    }
  }
  int cur = 0;
  for (int i = 0; i < 8; i++){
    const bool pf = i < 7;
    uint4 pb[4];
    uint4 av;
    int k1 = (i + 1) * 32;
    if (pf){
      if (t < 64) av = combineA(k1);
      #pragma unroll
      for (int j = 0; j < 4; j++){
        int col = j * 64 + bq_;
        pb[j] = *(const uint4*)&Wt[(size_t)col * 256 + k1 + bchk * 8];
      }
    }
    wg_barrier();
    union { uint4 u; short8_t s; } a, b;
    a.u = *(const uint4*)&Ab[cur][afr];
    #pragma unroll
    for (int fn = 0; fn < 4; fn++){
      b.u = *(const uint4*)&Bb[cur][bfr[fn]];
      acc[fn] = __builtin_amdgcn_mfma_f32_16x16x32_bf16(a.s, b.s, acc[fn], 0, 0, 0);
    }
    if (pf){
      if (t < 64) *(uint4*)&Ab[cur ^ 1][aswz] = av;
      #pragma unroll
      for (int j = 0; j < 4; j++){
        int col = j * 64 + bq_;
        *(uint4*)&Bb[cur ^ 1][col * 32 + ((bchk ^ ((col >> 1) & 3)) * 8)] = pb[j];
      }
      cur ^= 1;
    }
  }

  // epilogue: bias + residual, register-space LN, result -> LDS tile hl
  float vv[4][4];
  #pragma unroll
  for (int fn = 0; fn < 4; fn++){
    int col = w * 64 + fn * 16 + c16;
    float bia = bo[col];
    #pragma unroll
    for (int r = 0; r < 4; r++)
      vv[fn][r] = acc[fn][r] + bia + h2f[(size_t)(bm * 16 + g * 4 + r) * 256 + col];
  }
  #pragma unroll
  for (int r = 0; r < 4; r++){
    float a = 0.f, b = 0.f;
    #pragma unroll
    for (int fn = 0; fn < 4; fn++){ a += vv[fn][r]; b += vv[fn][r] * vv[fn][r]; }
    a = rowsum16(a); b = rowsum16(b);
    if (c16 == 0){ red1[w][g * 4 + r] = a; red2[w][g * 4 + r] = b; }
  }
  __syncthreads();
  #pragma unroll
  for (int r = 0; r < 4; r++){
    int row = g * 4 + r;
    float S1 = red1[0][row] + red1[1][row] + red1[2][row] + red1[3][row];
    float S2 = red2[0][row] + red2[1][row] + red2[2][row] + red2[3][row];
    float mean = S1 * (1.f / 256.f);
    float var = S2 * (1.f / 256.f) - mean * mean;
    float rs = rsqrtf(var + 1e-5f);
    #pragma unroll
    for (int fn = 0; fn < 4; fn++){
      int col = w * 64 + fn * 16 + c16;
      hl[row * 264 + col] = f2bf((vv[fn][r] - mean) * rs * gg[col] + bb[col]);
    }
  }

  // ---- classifier phase: c1 = relu(hl @ W1 + b1); out = c1 @ w2 + b2 ----
  wg_barrier();
  int cfr[2];
  #pragma unroll
  for (int fn = 0; fn < 2; fn++){
    int col = w * 32 + fn * 16 + c16;
    cfr[fn] = col * 32 + ((g ^ ((col >> 1) & 3)) * 8);
  }
  f32x4_t cacc[2] = {};
  {
    #pragma unroll
    for (int j = 0; j < 2; j++){
      int col = j * 64 + bq_;
      *(uint4*)&Cb[0][col * 32 + ((bchk ^ ((col >> 1) & 3)) * 8)] = *(const uint4*)&Wt1[(size_t)col * 256 + bchk * 8];
    }
  }
  cur = 0;
  for (int i = 0; i < 8; i++){
    const bool pf = i < 7;
    uint4 pb[2];
    if (pf){
      int k1 = (i + 1) * 32;
      #pragma unroll
      for (int j = 0; j < 2; j++){
        int col = j * 64 + bq_;
        pb[j] = *(const uint4*)&Wt1[(size_t)col * 256 + k1 + bchk * 8];
      }
    }
    wg_barrier();
    union { uint4 u; short8_t s; } a, b;
    a.u = *(const uint4*)&hl[c16 * 264 + i * 32 + g * 8];
    #pragma unroll
    for (int fn = 0; fn < 2; fn++){
      b.u = *(const uint4*)&Cb[cur][cfr[fn]];
      cacc[fn] = __builtin_amdgcn_mfma_f32_16x16x32_bf16(a.s, b.s, cacc[fn], 0, 0, 0);
    }
    if (pf){
      #pragma unroll
      for (int j = 0; j < 2; j++){
        int col = j * 64 + bq_;
        *(uint4*)&Cb[cur ^ 1][col * 32 + ((bchk ^ ((col >> 1) & 3)) * 8)] = pb[j];
      }
      cur ^= 1;
    }
  }
  float cv[2][4];
  #pragma unroll
  for (int fn = 0; fn < 2; fn++){
    int col = w * 32 + fn * 16 + c16;
    float bia = b1[col];
    #pragma unroll
    for (int r = 0; r < 4; r++) cv[fn][r] = fmaxf(cacc[fn][r] + bia, 0.f);
  }
  float w20 = w2[(w * 32 + c16) * 2],      w21 = w2[(w * 32 + c16) * 2 + 1];
  float w30 = w2[(w * 32 + 16 + c16) * 2], w31 = w2[(w * 32 + 16 + c16) * 2 + 1];
  #pragma unroll
  for (int r = 0; r < 4; r++){
    float a0 = cv[0][r] * w20 + cv[1][r] * w30;
    float a1 = cv[0][r] * w21 + cv[1][r] * w31;
    a0 = rowsum16(a0); a1 = rowsum16(a1);
    if (c16 == 0){ cred0[w][g * 4 + r] = a0; cred1[w][g * 4 + r] = a1; }
  }
  __syncthreads();
  if (t < 16){
    float q0 = cred0[0][t] + cred0[1][t] + cred0[2][t] + cred0[3][t] + b2[0];
    float q1 = cred1[0][t] + cred1[1][t] + cred1[2][t] + cred1[3][t] + b2[1];
    out[(size_t)(bm * 16 + t) * 2]     = q0;
    out[(size_t)(bm * 16 + t) * 2 + 1] = q1;
  }
}

// ---------- host ----------
extern "C" void kernel_launch(void* const* d_in, const int* in_sizes, int n_in,
                              void* d_out, int out_size, void* d_ws, size_t ws_size,
                              hipStream_t stream){
  const float* x      = (const float*)d_in[0];
  const int*   ei     = (const int*)d_in[1];
  const float* emb_w  = (const float*)d_in[2];
  const float* emb_b  = (const float*)d_in[3];
  const float* g1_wl  = (const float*)d_in[4];
  const float* g1_wr  = (const float*)d_in[5];
  const float* g1_att = (const float*)d_in[6];
  const float* g1_b   = (const float*)d_in[7];
  const float* g2_wl  = (const float*)d_in[8];
  const float* g2_wr  = (const float*)d_in[9];
  const float* g2_att = (const float*)d_in[10];
  const float* g2_b   = (const float*)d_in[11];
  const float* wq     = (const float*)d_in[12];
  const float* wk     = (const float*)d_in[13];
  const float* wv     = (const float*)d_in[14];
  const float* bq     = (const float*)d_in[15];
  const float* bk     = (const float*)d_in[16];
  const float* bv     = (const float*)d_in[17];
  const float* wo     = (const float*)d_in[18];
  const float* bo     = (const float*)d_in[19];
  const float* ln_g   = (const float*)d_in[20];
  const float* ln_b   = (const float*)d_in[21];
  const float* cls_w1 = (const float*)d_in[22];
  const float* cls_b1 = (const float*)d_in[23];
  const float* cls_w2 = (const float*)d_in[24];
  const float* cls_b2 = (const float*)d_in[25];
  float* out = (float*)d_out;

  char* wsb = (char*)d_ws;
  size_t o = 0;
  auto take = [&](size_t bytes) -> char* {
    char* r = wsb + o; o += (bytes + 255) & ~(size_t)255; return r;
  };
  unsigned short* wt_emb  = (unsigned short*)take(768 * 256 * 2);
  unsigned short* wt_wl1  = (unsigned short*)take(256 * 256 * 2);
  unsigned short* wt_wr1  = (unsigned short*)take(256 * 256 * 2);
  unsigned short* wt_wl2  = (unsigned short*)take(256 * 256 * 2);
  unsigned short* wt_wr2  = (unsigned short*)take(256 * 256 * 2);
  unsigned short* wt_wq   = (unsigned short*)take(256 * 256 * 2);
  unsigned short* wt_wk   = (unsigned short*)take(256 * 256 * 2);
  unsigned short* wt_wv   = (unsigned short*)take(256 * 256 * 2);
  unsigned short* wt_wo   = (unsigned short*)take(256 * 256 * 2);
  unsigned short* wt_cls1 = (unsigned short*)take(256 * 128 * 2);
  unsigned short* x_bf    = (unsigned short*)take((size_t)4096 * 768 * 2);
  unsigned short* h0_bf   = (unsigned short*)take((size_t)4096 * 256 * 2);
  unsigned short* xs1_bf  = (unsigned short*)take((size_t)4096 * 256 * 2);
  unsigned short* xd1_bf  = (unsigned short*)take((size_t)4096 * 256 * 2);
  unsigned short* h1_bf   = (unsigned short*)take((size_t)4096 * 256 * 2);
  unsigned short* xs2_bf  = (unsigned short*)take((size_t)4096 * 256 * 2);
  unsigned short* xd2_bf  = (unsigned short*)take((size_t)4096 * 256 * 2);
  unsigned short* h2_bf   = (unsigned short*)take((size_t)4096 * 256 * 2);
  float*          h2_f    = (float*)take((size_t)4096 * 256 * 4);
  unsigned short* q_bf    = (unsigned short*)take((size_t)4096 * 256 * 2);
  unsigned short* k_bf    = (unsigned short*)take((size_t)4096 * 256 * 2);
  unsigned short* vt_bf   = (unsigned short*)take((size_t)4096 * 256 * 2);
  int* cnt  = (int*)take(4096 * 4);
  int* csrc = (int*)take((size_t)N_NODES * BUCKET_CAP * 4);
  _Float16* Opart = (_Float16*)take((size_t)SPLITS * 4 * N_NODES * 64 * 2);
  float*    Ol    = (float*)take((size_t)SPLITS * 4 * N_NODES * 4);

  // prep: x convert + weight transposes + zero cnt
  TJobs TJ;
  TJob tj[10] = {
    { emb_w,  wt_emb,  768, 256, 0 },
    { g1_wl,  wt_wl1,  256, 256, 0 },
    { g1_wr,  wt_wr1,  256, 256, 0 },
    { g2_wl,  wt_wl2,  256, 256, 0 },
    { g2_wr,  wt_wr2,  256, 256, 0 },
    { wq,     wt_wq,   256, 256, 0 },
    { wk,     wt_wk,   256, 256, 0 },
    { wv,     wt_wv,   256, 256, 0 },
    { wo,     wt_wo,   256, 256, 0 },
    { cls_w1, wt_cls1, 256, 128, 0 },
  };
  int tb = 0;
  for (int i = 0; i < 10; i++){
    tj[i].tile0 = tb;
    tb += (tj[i].rows >> 6) * (tj[i].cols >> 6);
    TJ.j[i] = tj[i];
  }
  prep_kernel<<<3072 + tb + 16, 256, 0, stream>>>(x, x_bf, TJ, tb, cnt);

  // bucket scatter (no CSR)
  scatter_kernel<<<(E_TOTAL + 255) / 256, 256, 0, stream>>>(ei, cnt, csrc);

  GJobs J;
  // embedding GEMM
  J = {}; J.j[0] = { wt_emb, emb_b, nullptr, h0_bf, nullptr, 1.f };
  gemm_kernel<<<dim3(64, 4, 1), 256, 0, stream>>>(x_bf, J, 768, 256, 0);
  // GAT1
  J = {}; J.j[0] = { wt_wl1, nullptr, nullptr, xs1_bf, nullptr, 1.f }; J.j[1] = { wt_wr1, nullptr, nullptr, xd1_bf, nullptr, 1.f };
  gemm_kernel<<<dim3(64, 4, 2), 256, 0, stream>>>(h0_bf, J, 256, 256, 0);
  gat_gather<<<4096, 256, 0, stream>>>(xs1_bf, xd1_bf, g1_att, g1_b, cnt, csrc, h1_bf, nullptr);
  // GAT2
  J = {}; J.j[0] = { wt_wl2, nullptr, nullptr, xs2_bf, nullptr, 1.f }; J.j[1] = { wt_wr2, nullptr, nullptr, xd2_bf, nullptr, 1.f };
  gemm_kernel<<<dim3(64, 4, 2), 256, 0, stream>>>(h1_bf, J, 256, 256, 0);
  gat_gather<<<4096, 256, 0, stream>>>(xs2_bf, xd2_bf, g2_att, g2_b, cnt, csrc, h2_bf, h2_f);
  // QKV (Q prescaled by 0.125*log2e for exp2-softmax; V written transposed via outT)
  J = {};
  J.j[0] = { wt_wq, bq, nullptr, q_bf, nullptr, 0.125f * 1.44269504f };
  J.j[1] = { wt_wk, bk, nullptr, k_bf, nullptr, 1.f };
  J.j[2] = { wt_wv, bv, nullptr, nullptr, vt_bf, 1.f };
  gemm_kernel<<<dim3(64, 4, 3), 256, 0, stream>>>(h2_bf, J, 256, 256, 0);
  // attention (f16 partials, SPLITS=12, 48KB LDS -> 3 blocks/CU, VGPR cap 128)
  attn_kernel<<<dim3(16, 4, SPLITS), 512, 0, stream>>>(q_bf, k_bf, vt_bf, Opart, Ol);
  // Wo + combine + residual + LN + classifier
  wo_ln_cls_kernel<<<256, 256, 0, stream>>>(Opart, Ol, wt_wo, bo, h2_f, ln_g, ln_b,
                                            wt_cls1, cls_b1, cls_w2, cls_b2, out);

  (void)in_sizes; (void)n_in; (void)out_size; (void)ws_size;
}